// Round 2
// baseline (415.648 us; speedup 1.0000x reference)
//
#include <hip/hip_runtime.h>

typedef unsigned short u16;
typedef unsigned short u16x8 __attribute__((ext_vector_type(8)));
typedef unsigned short u16x4 __attribute__((ext_vector_type(4)));
typedef short s16x8 __attribute__((ext_vector_type(8)));
typedef float f32x4 __attribute__((ext_vector_type(4)));

__device__ __forceinline__ u16 f2b(float f){
  unsigned u = __builtin_bit_cast(unsigned, f);
  u += 0x7fffu + ((u >> 16) & 1u);
  return (u16)(u >> 16);
}

#define MFMA(c, a, b) (c) = __builtin_amdgcn_mfma_f32_16x16x32_bf16((a), (b), (c), 0, 0, 0)

// ---------------- cast hidden_states f32 -> bf16 ----------------
__global__ void k_cast(const float* __restrict__ src, u16* __restrict__ dst, int n8){
  int i = blockIdx.x * blockDim.x + threadIdx.x;
  if (i >= n8) return;
  const float4* s = (const float4*)(src + (size_t)i * 8);
  float4 a = s[0], b = s[1];
  u16x8 o;
  o[0]=f2b(a.x); o[1]=f2b(a.y); o[2]=f2b(a.z); o[3]=f2b(a.w);
  o[4]=f2b(b.x); o[5]=f2b(b.y); o[6]=f2b(b.z); o[7]=f2b(b.w);
  *(u16x8*)(dst + (size_t)i * 8) = o;
}

// ------- transpose+cast: src (K x N f32) -> dst (N x K bf16) -------
__global__ void k_transpose(const float* __restrict__ src, u16* __restrict__ dst, int K, int N){
  __shared__ float t[32][33];
  int n0 = blockIdx.x * 32, k0 = blockIdx.y * 32;
  int c = threadIdx.x & 31, r4 = threadIdx.x >> 5;
  #pragma unroll
  for (int p = 0; p < 4; ++p){
    int r = r4 + p * 8;
    t[r][c] = src[(size_t)(k0 + r) * N + n0 + c];
  }
  __syncthreads();
  #pragma unroll
  for (int p = 0; p < 4; ++p){
    int r = r4 + p * 8;
    dst[(size_t)(n0 + r) * K + k0 + c] = f2b(t[c][r]);
  }
}

// ---------------- GEMM: C(MxN,f32) = A(MxK,bf16) * BT(NxK,bf16)^T ----------------
// 128x128 tile, BK=64, 4 waves (2x2 of 64x64), global_load_lds w/ pre-swizzled source.
__global__ __launch_bounds__(256, 2) void k_gemm(const u16* __restrict__ A, const u16* __restrict__ BT,
                                                 float* __restrict__ C, int M, int N, int K){
  __shared__ __align__(16) char sm[32768];
  char* sA = sm;
  char* sB = sm + 16384;
  const int tid = threadIdx.x;
  const int lane = tid & 63, w = tid >> 6;
  const int wm = w >> 1, wn = w & 1;
  const int m0 = blockIdx.y * 128, n0 = blockIdx.x * 128;
  f32x4 acc[4][4] = {};
  const int nk = K >> 6;
  for (int kt = 0; kt < nk; ++kt){
    const int k0 = kt << 6;
    #pragma unroll
    for (int i = 0; i < 4; ++i){
      const int q = i * 256 + tid;
      const int r = q >> 3, cch = q & 7;
      const int sw = (cch ^ (r & 7)) << 3;   // pre-swizzled source chunk (elems)
      const unsigned lofs = (unsigned)(i * 4096 + w * 1024); // wave-uniform LDS base
      __builtin_amdgcn_global_load_lds(
          (const __attribute__((address_space(1))) void*)(A + (size_t)(m0 + r) * K + k0 + sw),
          (__attribute__((address_space(3))) void*)(sA + lofs), 16, 0, 0);
      __builtin_amdgcn_global_load_lds(
          (const __attribute__((address_space(1))) void*)(BT + (size_t)(n0 + r) * K + k0 + sw),
          (__attribute__((address_space(3))) void*)(sB + lofs), 16, 0, 0);
    }
    __syncthreads();
    #pragma unroll
    for (int s = 0; s < 2; ++s){
      s16x8 af[4], bfv[4];
      #pragma unroll
      for (int mi = 0; mi < 4; ++mi){
        const int r = wm * 64 + mi * 16 + (lane & 15);
        const int cg = s * 4 + (lane >> 4);
        af[mi] = *(const s16x8*)(sA + r * 128 + ((cg ^ (r & 7)) << 4));
      }
      #pragma unroll
      for (int ni = 0; ni < 4; ++ni){
        const int r = wn * 64 + ni * 16 + (lane & 15);
        const int cg = s * 4 + (lane >> 4);
        bfv[ni] = *(const s16x8*)(sB + r * 128 + ((cg ^ (r & 7)) << 4));
      }
      #pragma unroll
      for (int mi = 0; mi < 4; ++mi)
        #pragma unroll
        for (int ni = 0; ni < 4; ++ni)
          MFMA(acc[mi][ni], af[mi], bfv[ni]);
    }
    __syncthreads();
  }
  #pragma unroll
  for (int mi = 0; mi < 4; ++mi)
    #pragma unroll
    for (int ni = 0; ni < 4; ++ni)
      #pragma unroll
      for (int i = 0; i < 4; ++i){
        const int row = m0 + wm * 64 + mi * 16 + (lane >> 4) * 4 + i;
        const int col = n0 + wn * 64 + ni * 16 + (lane & 15);
        C[(size_t)row * N + col] = acc[mi][ni][i];
      }
}

// ---------------- fused RMSNorm + RoPE + split/cast ----------------
__global__ __launch_bounds__(256, 4) void k_rmsrope(const float* __restrict__ qkv,
    const float* __restrict__ cosT, const float* __restrict__ sinT,
    const float* __restrict__ qw, const float* __restrict__ kw,
    u16* __restrict__ qout, u16* __restrict__ kout, u16* __restrict__ vout){
  const int bs = blockIdx.x;
  const int b = bs >> 11, s = bs & 2047;
  const int lane = threadIdx.x & 63, w = threadIdx.x >> 6;
  const float* row = qkv + (size_t)bs * 4096;
  const float c1 = cosT[(size_t)bs * 128 + lane];
  const float s1 = sinT[(size_t)bs * 128 + lane];
  const float c2 = cosT[(size_t)bs * 128 + 64 + lane];
  const float s2 = sinT[(size_t)bs * 128 + 64 + lane];
  const float wq1 = qw[lane], wq2 = qw[64 + lane];
  const float wk1 = kw[lane], wk2 = kw[64 + lane];
  for (int u = w; u < 32; u += 4){
    if (u < 24){
      const int isq = (u < 16);
      const int base = isq ? u * 128 : 2048 + (u - 16) * 128;
      float x1 = row[base + lane], x2 = row[base + 64 + lane];
      float ss = x1 * x1 + x2 * x2;
      #pragma unroll
      for (int m = 1; m < 64; m <<= 1) ss += __shfl_xor(ss, m);
      float rsq = rsqrtf(ss * (1.0f / 128.0f) + 1e-6f);
      float n1 = x1 * rsq * (isq ? wq1 : wk1);
      float n2 = x2 * rsq * (isq ? wq2 : wk2);
      float o1 = n1 * c1 - n2 * s1;   // rotate_half: first half gets -x2*sin
      float o2 = n2 * c2 + n1 * s2;   // second half gets +x1*sin
      if (isq){
        size_t o = ((size_t)(b * 16 + u) * 2048 + s) * 128;
        qout[o + lane] = f2b(o1); qout[o + 64 + lane] = f2b(o2);
      } else {
        size_t o = ((size_t)(b * 8 + (u - 16)) * 2048 + s) * 128;
        kout[o + lane] = f2b(o1); kout[o + 64 + lane] = f2b(o2);
      }
    } else {
      const int j = u - 24;
      size_t o = ((size_t)(b * 8 + j) * 2048 + s) * 128;
      vout[o + lane] = f2b(row[3072 + j * 128 + lane]);
      vout[o + 64 + lane] = f2b(row[3072 + j * 128 + 64 + lane]);
    }
  }
}

// ---------------- flash attention (causal, GQA 2:1) ----------------
__global__ __launch_bounds__(256, 2) void k_attn(const u16* __restrict__ qb, const u16* __restrict__ kb,
                                                 const u16* __restrict__ vb, u16* __restrict__ ob){
  __shared__ __align__(16) u16 sK[32 * 136];   // stride 136: 2-way on B-frag reads
  __shared__ __align__(16) u16 sV[32 * 132];   // stride 132: 2-way on scalar V reads
  __shared__ __align__(16) u16 sP[4][16 * 40]; // per-wave P buffer, stride 40
  const int tid = threadIdx.x, lane = tid & 63, w = tid >> 6;
  const int qt = blockIdx.x & 31;
  const int h  = (blockIdx.x >> 5) & 15;
  const int b  = blockIdx.x >> 9;
  const int kvh = h >> 1;
  const u16* Q  = qb + ((size_t)(b * 16 + h)  * 2048) * 128;
  const u16* Kg = kb + ((size_t)(b * 8 + kvh) * 2048) * 128;
  const u16* Vg = vb + ((size_t)(b * 8 + kvh) * 2048) * 128;
  const int qrow0 = qt * 64 + w * 16;
  s16x8 qf[4];
  #pragma unroll
  for (int kc = 0; kc < 4; ++kc)
    qf[kc] = *(const s16x8*)(Q + (size_t)(qrow0 + (lane & 15)) * 128 + kc * 32 + (lane >> 4) * 8);
  f32x4 acc[8] = {};
  float mx[4], lsum[4];
  #pragma unroll
  for (int i = 0; i < 4; ++i){ mx[i] = -1e30f; lsum[i] = 0.f; }
  const int nkt = qt * 2 + 2;
  for (int kt = 0; kt < nkt; ++kt){
    { // ---- stage K,V tile (32 keys x 128) ----
      int r = tid >> 3, c0 = (tid & 7) * 16;
      const u16* gk = Kg + (size_t)(kt * 32 + r) * 128 + c0;
      const u16* gv = Vg + (size_t)(kt * 32 + r) * 128 + c0;
      u16x8 k1 = *(const u16x8*)gk;
      u16x8 k2 = *(const u16x8*)(gk + 8);
      u16x8 v1 = *(const u16x8*)gv;
      u16x8 v2 = *(const u16x8*)(gv + 8);
      *(u16x8*)(sK + r * 136 + c0) = k1;
      *(u16x8*)(sK + r * 136 + c0 + 8) = k2;
      u16* pv = sV + r * 132 + c0;   // 8B-aligned rows
      *(u16x4*)(pv)      = __builtin_shufflevector(v1, v1, 0, 1, 2, 3);
      *(u16x4*)(pv + 4)  = __builtin_shufflevector(v1, v1, 4, 5, 6, 7);
      *(u16x4*)(pv + 8)  = __builtin_shufflevector(v2, v2, 0, 1, 2, 3);
      *(u16x4*)(pv + 12) = __builtin_shufflevector(v2, v2, 4, 5, 6, 7);
    }
    __syncthreads();
    // ---- QK^T: 16x32 scores per wave ----
    f32x4 sc[2] = {};
    #pragma unroll
    for (int nt = 0; nt < 2; ++nt)
      #pragma unroll
      for (int kc = 0; kc < 4; ++kc){
        s16x8 kf = *(const s16x8*)(sK + (nt * 16 + (lane & 15)) * 136 + kc * 32 + (lane >> 4) * 8);
        MFMA(sc[nt], qf[kc], kf);
      }
    // ---- online softmax (fp32) ----
    float p[2][4], rm[4];
    #pragma unroll
    for (int i = 0; i < 4; ++i) rm[i] = -1e30f;
    const int qbase = qrow0 + (lane >> 4) * 4;
    #pragma unroll
    for (int nt = 0; nt < 2; ++nt){
      int key = kt * 32 + nt * 16 + (lane & 15);
      #pragma unroll
      for (int i = 0; i < 4; ++i){
        float v = sc[nt][i] * 0.08838834764831845f;  // HD^-0.5
        if (key > qbase + i) v = -1e30f;             // causal (exact vs -1e9 mask)
        p[nt][i] = v;
        rm[i] = fmaxf(rm[i], v);
      }
    }
    #pragma unroll
    for (int m = 1; m < 16; m <<= 1)
      #pragma unroll
      for (int i = 0; i < 4; ++i) rm[i] = fmaxf(rm[i], __shfl_xor(rm[i], m));
    float alpha[4];
    #pragma unroll
    for (int i = 0; i < 4; ++i){
      float mn = fmaxf(mx[i], rm[i]);
      alpha[i] = __expf(mx[i] - mn);
      mx[i] = mn;
    }
    float rs[4] = {0.f, 0.f, 0.f, 0.f};
    #pragma unroll
    for (int nt = 0; nt < 2; ++nt)
      #pragma unroll
      for (int i = 0; i < 4; ++i){
        float e = __expf(p[nt][i] - mx[i]);
        p[nt][i] = e;
        rs[i] += e;
      }
    #pragma unroll
    for (int m = 1; m < 16; m <<= 1)
      #pragma unroll
      for (int i = 0; i < 4; ++i) rs[i] += __shfl_xor(rs[i], m);
    #pragma unroll
    for (int i = 0; i < 4; ++i) lsum[i] = lsum[i] * alpha[i] + rs[i];
    // ---- P -> LDS (D-layout) then re-read in A-layout ----
    u16* sPw = sP[w];
    #pragma unroll
    for (int nt = 0; nt < 2; ++nt)
      #pragma unroll
      for (int i = 0; i < 4; ++i)
        sPw[((lane >> 4) * 4 + i) * 40 + nt * 16 + (lane & 15)] = f2b(p[nt][i]);
    __syncthreads();
    #pragma unroll
    for (int c = 0; c < 8; ++c)
      #pragma unroll
      for (int i = 0; i < 4; ++i) acc[c][i] *= alpha[i];
    s16x8 pf = *(const s16x8*)(sPw + (lane & 15) * 40 + (lane >> 4) * 8);
    #pragma unroll
    for (int c = 0; c < 8; ++c){
      s16x8 vf;
      #pragma unroll
      for (int j = 0; j < 8; ++j)
        vf[j] = (short)sV[((lane >> 4) * 8 + j) * 132 + c * 16 + (lane & 15)];
      MFMA(acc[c], pf, vf);
    }
    __syncthreads();
  }
  // ---- epilogue: O/l -> (B,S,H*HD) bf16 ----
  #pragma unroll
  for (int c = 0; c < 8; ++c)
    #pragma unroll
    for (int i = 0; i < 4; ++i){
      int row = qrow0 + (lane >> 4) * 4 + i;
      int col = h * 128 + c * 16 + (lane & 15);
      ob[((size_t)(b * 2048) + row) * 2048 + col] = f2b(acc[c][i] / lsum[i]);
    }
}

extern "C" void kernel_launch(void* const* d_in, const int* in_sizes, int n_in,
                              void* d_out, int out_size, void* d_ws, size_t ws_size,
                              hipStream_t stream){
  const float* hs   = (const float*)d_in[0];
  const float* cosT = (const float*)d_in[1];
  const float* sinT = (const float*)d_in[2];
  // d_in[3] attention_mask: pure causal, implemented analytically
  const float* Wq = (const float*)d_in[4];
  const float* Wk = (const float*)d_in[5];
  const float* Wv = (const float*)d_in[6];
  const float* Wo = (const float*)d_in[7];
  const float* qw = (const float*)d_in[8];
  const float* kw = (const float*)d_in[9];
  float* out = (float*)d_out;
  char* ws = (char*)d_ws;

  // workspace layout (104 MB), with aliasing:
  u16*   hsb   = (u16*)(ws);                         // 16 MB  (later: q bf16)
  u16*   wqkvT = (u16*)(ws + 16777216);              // 16 MB  (later: k,v bf16)
  u16*   woT   = (u16*)(ws + 33554432);              // 8 MB
  float* qkv   = (float*)(ws + 41943040);            // 64 MB  (later: attn out bf16)
  u16*   qb    = hsb;
  u16*   kb2   = (u16*)(ws + 16777216);
  u16*   vb2   = (u16*)(ws + 16777216 + 8388608);
  u16*   attnb = (u16*)(ws + 41943040);

  k_cast<<<4096, 256, 0, stream>>>(hs, hsb, 1048576);
  k_transpose<<<dim3(64, 64),  256, 0, stream>>>(Wq, wqkvT,                       2048, 2048);
  k_transpose<<<dim3(32, 64),  256, 0, stream>>>(Wk, wqkvT + (size_t)2048 * 2048, 2048, 1024);
  k_transpose<<<dim3(32, 64),  256, 0, stream>>>(Wv, wqkvT + (size_t)3072 * 2048, 2048, 1024);
  k_transpose<<<dim3(64, 64),  256, 0, stream>>>(Wo, woT,                         2048, 2048);
  k_gemm<<<dim3(32, 32), 256, 0, stream>>>(hsb, wqkvT, qkv, 4096, 4096, 2048);
  k_rmsrope<<<4096, 256, 0, stream>>>(qkv, cosT, sinT, qw, kw, qb, kb2, vb2);
  k_attn<<<1024, 256, 0, stream>>>(qb, kb2, vb2, attnb);
  k_gemm<<<dim3(16, 32), 256, 0, stream>>>(attnb, woT, out, 4096, 2048, 2048);
}

// Round 3
// 277.151 us; speedup vs baseline: 1.4997x; 1.4997x over previous
//
#include <hip/hip_runtime.h>

typedef unsigned short u16;
typedef unsigned short u16x8 __attribute__((ext_vector_type(8)));
typedef unsigned short u16x4 __attribute__((ext_vector_type(4)));
typedef short s16x8 __attribute__((ext_vector_type(8)));
typedef float f32x4 __attribute__((ext_vector_type(4)));

__device__ __forceinline__ u16 f2b(float f){
  unsigned u = __builtin_bit_cast(unsigned, f);
  u += 0x7fffu + ((u >> 16) & 1u);
  return (u16)(u >> 16);
}

#define MFMA(c, a, b) (c) = __builtin_amdgcn_mfma_f32_16x16x32_bf16((a), (b), (c), 0, 0, 0)

// ---------------- cast hidden_states f32 -> bf16 ----------------
__global__ void k_cast(const float* __restrict__ src, u16* __restrict__ dst, int n8){
  int i = blockIdx.x * blockDim.x + threadIdx.x;
  if (i >= n8) return;
  const float4* s = (const float4*)(src + (size_t)i * 8);
  float4 a = s[0], b = s[1];
  u16x8 o;
  o[0]=f2b(a.x); o[1]=f2b(a.y); o[2]=f2b(a.z); o[3]=f2b(a.w);
  o[4]=f2b(b.x); o[5]=f2b(b.y); o[6]=f2b(b.z); o[7]=f2b(b.w);
  *(u16x8*)(dst + (size_t)i * 8) = o;
}

// ------- transpose+cast: src (K x N f32) -> dst (N x K bf16) -------
__global__ void k_transpose(const float* __restrict__ src, u16* __restrict__ dst, int K, int N){
  __shared__ float t[32][33];
  int n0 = blockIdx.x * 32, k0 = blockIdx.y * 32;
  int c = threadIdx.x & 31, r4 = threadIdx.x >> 5;
  #pragma unroll
  for (int p = 0; p < 4; ++p){
    int r = r4 + p * 8;
    t[r][c] = src[(size_t)(k0 + r) * N + n0 + c];
  }
  __syncthreads();
  #pragma unroll
  for (int p = 0; p < 4; ++p){
    int r = r4 + p * 8;
    dst[(size_t)(n0 + r) * K + k0 + c] = f2b(t[c][r]);
  }
}

// ---------------- GEMM: C(MxN,f32) = A(MxK,bf16) * BT(NxK,bf16)^T ----------------
__global__ __launch_bounds__(256, 2) void k_gemm(const u16* __restrict__ A, const u16* __restrict__ BT,
                                                 float* __restrict__ C, int M, int N, int K){
  __shared__ __align__(16) char sm[32768];
  char* sA = sm;
  char* sB = sm + 16384;
  const int tid = threadIdx.x;
  const int lane = tid & 63, w = tid >> 6;
  const int wm = w >> 1, wn = w & 1;
  const int m0 = blockIdx.y * 128, n0 = blockIdx.x * 128;
  f32x4 acc[4][4] = {};
  const int nk = K >> 6;
  for (int kt = 0; kt < nk; ++kt){
    const int k0 = kt << 6;
    #pragma unroll
    for (int i = 0; i < 4; ++i){
      const int q = i * 256 + tid;
      const int r = q >> 3, cch = q & 7;
      const int sw = (cch ^ (r & 7)) << 3;
      const unsigned lofs = (unsigned)(i * 4096 + w * 1024);
      __builtin_amdgcn_global_load_lds(
          (const __attribute__((address_space(1))) void*)(A + (size_t)(m0 + r) * K + k0 + sw),
          (__attribute__((address_space(3))) void*)(sA + lofs), 16, 0, 0);
      __builtin_amdgcn_global_load_lds(
          (const __attribute__((address_space(1))) void*)(BT + (size_t)(n0 + r) * K + k0 + sw),
          (__attribute__((address_space(3))) void*)(sB + lofs), 16, 0, 0);
    }
    __syncthreads();
    #pragma unroll
    for (int s = 0; s < 2; ++s){
      s16x8 af[4], bfv[4];
      #pragma unroll
      for (int mi = 0; mi < 4; ++mi){
        const int r = wm * 64 + mi * 16 + (lane & 15);
        const int cg = s * 4 + (lane >> 4);
        af[mi] = *(const s16x8*)(sA + r * 128 + ((cg ^ (r & 7)) << 4));
      }
      #pragma unroll
      for (int ni = 0; ni < 4; ++ni){
        const int r = wn * 64 + ni * 16 + (lane & 15);
        const int cg = s * 4 + (lane >> 4);
        bfv[ni] = *(const s16x8*)(sB + r * 128 + ((cg ^ (r & 7)) << 4));
      }
      #pragma unroll
      for (int mi = 0; mi < 4; ++mi)
        #pragma unroll
        for (int ni = 0; ni < 4; ++ni)
          MFMA(acc[mi][ni], af[mi], bfv[ni]);
    }
    __syncthreads();
  }
  #pragma unroll
  for (int mi = 0; mi < 4; ++mi)
    #pragma unroll
    for (int ni = 0; ni < 4; ++ni)
      #pragma unroll
      for (int i = 0; i < 4; ++i){
        const int row = m0 + wm * 64 + mi * 16 + (lane >> 4) * 4 + i;
        const int col = n0 + wn * 64 + ni * 16 + (lane & 15);
        C[(size_t)row * N + col] = acc[mi][ni][i];
      }
}

// ---------------- fused RMSNorm + RoPE + split/cast ----------------
__global__ __launch_bounds__(256, 4) void k_rmsrope(const float* __restrict__ qkv,
    const float* __restrict__ cosT, const float* __restrict__ sinT,
    const float* __restrict__ qw, const float* __restrict__ kw,
    u16* __restrict__ qout, u16* __restrict__ kout, u16* __restrict__ vout){
  const int bs = blockIdx.x;
  const int b = bs >> 11, s = bs & 2047;
  const int lane = threadIdx.x & 63, w = threadIdx.x >> 6;
  const float* row = qkv + (size_t)bs * 4096;
  const float c1 = cosT[(size_t)bs * 128 + lane];
  const float s1 = sinT[(size_t)bs * 128 + lane];
  const float c2 = cosT[(size_t)bs * 128 + 64 + lane];
  const float s2 = sinT[(size_t)bs * 128 + 64 + lane];
  const float wq1 = qw[lane], wq2 = qw[64 + lane];
  const float wk1 = kw[lane], wk2 = kw[64 + lane];
  for (int u = w; u < 32; u += 4){
    if (u < 24){
      const int isq = (u < 16);
      const int base = isq ? u * 128 : 2048 + (u - 16) * 128;
      float x1 = row[base + lane], x2 = row[base + 64 + lane];
      float ss = x1 * x1 + x2 * x2;
      #pragma unroll
      for (int m = 1; m < 64; m <<= 1) ss += __shfl_xor(ss, m);
      float rsq = rsqrtf(ss * (1.0f / 128.0f) + 1e-6f);
      float n1 = x1 * rsq * (isq ? wq1 : wk1);
      float n2 = x2 * rsq * (isq ? wq2 : wk2);
      float o1 = n1 * c1 - n2 * s1;
      float o2 = n2 * c2 + n1 * s2;
      if (isq){
        size_t o = ((size_t)(b * 16 + u) * 2048 + s) * 128;
        qout[o + lane] = f2b(o1); qout[o + 64 + lane] = f2b(o2);
      } else {
        size_t o = ((size_t)(b * 8 + (u - 16)) * 2048 + s) * 128;
        kout[o + lane] = f2b(o1); kout[o + 64 + lane] = f2b(o2);
      }
    } else {
      const int j = u - 24;
      size_t o = ((size_t)(b * 8 + j) * 2048 + s) * 128;
      vout[o + lane] = f2b(row[3072 + j * 128 + lane]);
      vout[o + 64 + lane] = f2b(row[3072 + j * 128 + 64 + lane]);
    }
  }
}

// ---------------- flash attention v2 (causal, GQA 2:1) ----------------
// 512 blocks: (b, h, pair). Each block processes q-tiles qt=pair and qt=31-pair
// sequentially -> exactly 33 kv-tile iterations per block (perfect balance).
// KVBLK=64. K: global_load_lds, m97 XOR layout. V: LDS-transposed, swizzled,
// b128 B-frag reads. P: per-wave swizzled LDS, b128 A-frag reads.
__global__ __launch_bounds__(256, 2) void k_attn(const u16* __restrict__ qb, const u16* __restrict__ kb,
                                                 const u16* __restrict__ vb, u16* __restrict__ ob){
  __shared__ __align__(16) u16 sK[64 * 128];   // [key][d], chunk-swizzled (m97)
  __shared__ __align__(16) u16 sVt[128 * 64];  // [d][key], key-chunk swizzled
  __shared__ __align__(16) u16 sP[4][16 * 64]; // per-wave [q][key], swizzled
  const int tid = threadIdx.x, lane = tid & 63, w = tid >> 6;
  const int pi = blockIdx.x & 15;
  const int h  = (blockIdx.x >> 4) & 15;
  const int b  = blockIdx.x >> 8;
  const int kvh = h >> 1;
  const u16* Q  = qb + ((size_t)(b * 16 + h)  * 2048) * 128;
  const u16* Kg = kb + ((size_t)(b * 8 + kvh) * 2048) * 128;
  const u16* Vg = vb + ((size_t)(b * 8 + kvh) * 2048) * 128;
  u16* sPw = sP[w];

  for (int ph = 0; ph < 2; ++ph){
    const int qt = ph ? (31 - pi) : pi;
    const int qrow0 = qt * 64 + w * 16;
    s16x8 qf[4];
    #pragma unroll
    for (int kc = 0; kc < 4; ++kc)
      qf[kc] = *(const s16x8*)(Q + (size_t)(qrow0 + (lane & 15)) * 128 + kc * 32 + (lane >> 4) * 8);
    f32x4 acc[8] = {};
    float mx[4], lsum[4];
    #pragma unroll
    for (int i = 0; i < 4; ++i){ mx[i] = -1e30f; lsum[i] = 0.f; }

    const int nkt = qt + 1;
    for (int kt = 0; kt < nkt; ++kt){
      // ---- stage K (64x128) via global_load_lds, pre-swizzled source ----
      #pragma unroll
      for (int i = 0; i < 4; ++i){
        const int q = i * 256 + tid;
        const int r = q >> 4, c = q & 15;
        const unsigned lofs = (unsigned)(i * 4096 + w * 1024);
        __builtin_amdgcn_global_load_lds(
            (const __attribute__((address_space(1))) void*)(Kg + (size_t)(kt * 64 + r) * 128 + ((c ^ (r & 7)) << 3)),
            (__attribute__((address_space(3))) void*)((char*)sK + lofs), 16, 0, 0);
      }
      // ---- stage V transposed: thread: key=lane, d-chunk = w*32 ----
      {
        const u16* gv = Vg + (size_t)(kt * 64 + lane) * 128 + w * 32;
        u16x8 vr0 = *(const u16x8*)(gv);
        u16x8 vr1 = *(const u16x8*)(gv + 8);
        u16x8 vr2 = *(const u16x8*)(gv + 16);
        u16x8 vr3 = *(const u16x8*)(gv + 24);
        const int kc8 = lane >> 3, ke = lane & 7;
        #pragma unroll
        for (int e = 0; e < 8; ++e){
          sVt[(w * 32 +  0 + e) * 64 + ((kc8 ^ e) << 3) + ke] = vr0[e];
          sVt[(w * 32 +  8 + e) * 64 + ((kc8 ^ e) << 3) + ke] = vr1[e];
          sVt[(w * 32 + 16 + e) * 64 + ((kc8 ^ e) << 3) + ke] = vr2[e];
          sVt[(w * 32 + 24 + e) * 64 + ((kc8 ^ e) << 3) + ke] = vr3[e];
        }
      }
      __syncthreads();
      // ---- QK^T: 16 q-rows x 64 keys per wave ----
      f32x4 sc4[4] = {};
      #pragma unroll
      for (int nt = 0; nt < 4; ++nt)
        #pragma unroll
        for (int kc = 0; kc < 4; ++kc){
          s16x8 kf = *(const s16x8*)(sK + (nt * 16 + (lane & 15)) * 128 + (((kc * 4 + (lane >> 4)) ^ (lane & 7)) << 3));
          MFMA(sc4[nt], qf[kc], kf);
        }
      // ---- online softmax ----
      float p[4][4], rm[4];
      #pragma unroll
      for (int i = 0; i < 4; ++i) rm[i] = -1e30f;
      const int qbase = qrow0 + (lane >> 4) * 4;
      #pragma unroll
      for (int nt = 0; nt < 4; ++nt){
        const int key = kt * 64 + nt * 16 + (lane & 15);
        #pragma unroll
        for (int i = 0; i < 4; ++i){
          float v = sc4[nt][i] * 0.08838834764831845f;
          if (key > qbase + i) v = -1e30f;
          p[nt][i] = v;
          rm[i] = fmaxf(rm[i], v);
        }
      }
      #pragma unroll
      for (int m = 1; m < 16; m <<= 1)
        #pragma unroll
        for (int i = 0; i < 4; ++i) rm[i] = fmaxf(rm[i], __shfl_xor(rm[i], m));
      float alpha[4];
      #pragma unroll
      for (int i = 0; i < 4; ++i){
        float mn = fmaxf(mx[i], rm[i]);
        alpha[i] = __expf(mx[i] - mn);
        mx[i] = mn;
      }
      float rs[4] = {0.f, 0.f, 0.f, 0.f};
      #pragma unroll
      for (int nt = 0; nt < 4; ++nt)
        #pragma unroll
        for (int i = 0; i < 4; ++i){
          float e = __expf(p[nt][i] - mx[i]);
          p[nt][i] = e;
          rs[i] += e;
        }
      #pragma unroll
      for (int m = 1; m < 16; m <<= 1)
        #pragma unroll
        for (int i = 0; i < 4; ++i) rs[i] += __shfl_xor(rs[i], m);
      #pragma unroll
      for (int i = 0; i < 4; ++i) lsum[i] = lsum[i] * alpha[i] + rs[i];
      // ---- P -> per-wave LDS (swizzled), no barrier needed ----
      #pragma unroll
      for (int nt = 0; nt < 4; ++nt)
        #pragma unroll
        for (int i = 0; i < 4; ++i){
          const int ql = (lane >> 4) * 4 + i;
          const int kl = nt * 16 + (lane & 15);
          sPw[ql * 64 + (((kl >> 3) ^ (ql & 7)) << 3) + (kl & 7)] = f2b(p[nt][i]);
        }
      // ---- rescale + PV ----
      #pragma unroll
      for (int c = 0; c < 8; ++c)
        #pragma unroll
        for (int i = 0; i < 4; ++i) acc[c][i] *= alpha[i];
      s16x8 pf[2];
      #pragma unroll
      for (int ks = 0; ks < 2; ++ks)
        pf[ks] = *(const s16x8*)(sPw + (lane & 15) * 64 + (((ks * 4 + (lane >> 4)) ^ (lane & 7)) << 3));
      #pragma unroll
      for (int c = 0; c < 8; ++c)
        #pragma unroll
        for (int ks = 0; ks < 2; ++ks){
          s16x8 vf = *(const s16x8*)(sVt + (c * 16 + (lane & 15)) * 64 + (((ks * 4 + (lane >> 4)) ^ (lane & 7)) << 3));
          MFMA(acc[c], pf[ks], vf);
        }
      __syncthreads();
    }
    // ---- epilogue for this q-tile ----
    #pragma unroll
    for (int c = 0; c < 8; ++c)
      #pragma unroll
      for (int i = 0; i < 4; ++i){
        const int row = qrow0 + (lane >> 4) * 4 + i;
        const int col = h * 128 + c * 16 + (lane & 15);
        ob[((size_t)(b * 2048) + row) * 2048 + col] = f2b(acc[c][i] / lsum[i]);
      }
  }
}

extern "C" void kernel_launch(void* const* d_in, const int* in_sizes, int n_in,
                              void* d_out, int out_size, void* d_ws, size_t ws_size,
                              hipStream_t stream){
  const float* hs   = (const float*)d_in[0];
  const float* cosT = (const float*)d_in[1];
  const float* sinT = (const float*)d_in[2];
  const float* Wq = (const float*)d_in[4];
  const float* Wk = (const float*)d_in[5];
  const float* Wv = (const float*)d_in[6];
  const float* Wo = (const float*)d_in[7];
  const float* qw = (const float*)d_in[8];
  const float* kw = (const float*)d_in[9];
  float* out = (float*)d_out;
  char* ws = (char*)d_ws;

  u16*   hsb   = (u16*)(ws);                         // 16 MB  (later: q bf16)
  u16*   wqkvT = (u16*)(ws + 16777216);              // 16 MB  (later: k,v bf16)
  u16*   woT   = (u16*)(ws + 33554432);              // 8 MB
  float* qkv   = (float*)(ws + 41943040);            // 64 MB  (later: attn out bf16)
  u16*   qb    = hsb;
  u16*   kb2   = (u16*)(ws + 16777216);
  u16*   vb2   = (u16*)(ws + 16777216 + 8388608);
  u16*   attnb = (u16*)(ws + 41943040);

  k_cast<<<4096, 256, 0, stream>>>(hs, hsb, 1048576);
  k_transpose<<<dim3(64, 64),  256, 0, stream>>>(Wq, wqkvT,                       2048, 2048);
  k_transpose<<<dim3(32, 64),  256, 0, stream>>>(Wk, wqkvT + (size_t)2048 * 2048, 2048, 1024);
  k_transpose<<<dim3(32, 64),  256, 0, stream>>>(Wv, wqkvT + (size_t)3072 * 2048, 2048, 1024);
  k_transpose<<<dim3(64, 64),  256, 0, stream>>>(Wo, woT,                         2048, 2048);
  k_gemm<<<dim3(32, 32), 256, 0, stream>>>(hsb, wqkvT, qkv, 4096, 4096, 2048);
  k_rmsrope<<<4096, 256, 0, stream>>>(qkv, cosT, sinT, qw, kw, qb, kb2, vb2);
  k_attn<<<512, 256, 0, stream>>>(qb, kb2, vb2, attnb);
  k_gemm<<<dim3(16, 32), 256, 0, stream>>>(attnb, woT, out, 4096, 2048, 2048);
}

// Round 4
// 274.389 us; speedup vs baseline: 1.5148x; 1.0101x over previous
//
#include <hip/hip_runtime.h>

typedef unsigned short u16;
typedef unsigned short u16x8 __attribute__((ext_vector_type(8)));
typedef short s16x8 __attribute__((ext_vector_type(8)));
typedef short s16x4 __attribute__((ext_vector_type(4)));
typedef float f32x4 __attribute__((ext_vector_type(4)));

__device__ __forceinline__ u16 f2b(float f){
  unsigned u = __builtin_bit_cast(unsigned, f);
  u += 0x7fffu + ((u >> 16) & 1u);
  return (u16)(u >> 16);
}

#define MFMA(c, a, b) (c) = __builtin_amdgcn_mfma_f32_16x16x32_bf16((a), (b), (c), 0, 0, 0)

__device__ __forceinline__ s16x8 cat8(s16x4 a, s16x4 b){
  return __builtin_shufflevector(a, b, 0, 1, 2, 3, 4, 5, 6, 7);
}

// ---------------- cast hidden_states f32 -> bf16 ----------------
__global__ void k_cast(const float* __restrict__ src, u16* __restrict__ dst, int n8){
  int i = blockIdx.x * blockDim.x + threadIdx.x;
  if (i >= n8) return;
  const float4* s = (const float4*)(src + (size_t)i * 8);
  float4 a = s[0], b = s[1];
  u16x8 o;
  o[0]=f2b(a.x); o[1]=f2b(a.y); o[2]=f2b(a.z); o[3]=f2b(a.w);
  o[4]=f2b(b.x); o[5]=f2b(b.y); o[6]=f2b(b.z); o[7]=f2b(b.w);
  *(u16x8*)(dst + (size_t)i * 8) = o;
}

// ------- transpose+cast: src (K x N f32) -> dst (N x K bf16) -------
__global__ void k_transpose(const float* __restrict__ src, u16* __restrict__ dst, int K, int N){
  __shared__ float t[32][33];
  int n0 = blockIdx.x * 32, k0 = blockIdx.y * 32;
  int c = threadIdx.x & 31, r4 = threadIdx.x >> 5;
  #pragma unroll
  for (int p = 0; p < 4; ++p){
    int r = r4 + p * 8;
    t[r][c] = src[(size_t)(k0 + r) * N + n0 + c];
  }
  __syncthreads();
  #pragma unroll
  for (int p = 0; p < 4; ++p){
    int r = r4 + p * 8;
    dst[(size_t)(n0 + r) * K + k0 + c] = f2b(t[c][r]);
  }
}

// ---------------- GEMM: C(MxN,f32) = A(MxK,bf16) * BT(NxK,bf16)^T ----------------
__global__ __launch_bounds__(256, 2) void k_gemm(const u16* __restrict__ A, const u16* __restrict__ BT,
                                                 float* __restrict__ C, int M, int N, int K){
  __shared__ __align__(16) char sm[32768];
  char* sA = sm;
  char* sB = sm + 16384;
  const int tid = threadIdx.x;
  const int lane = tid & 63, w = tid >> 6;
  const int wm = w >> 1, wn = w & 1;
  const int m0 = blockIdx.y * 128, n0 = blockIdx.x * 128;
  f32x4 acc[4][4] = {};
  const int nk = K >> 6;
  for (int kt = 0; kt < nk; ++kt){
    const int k0 = kt << 6;
    #pragma unroll
    for (int i = 0; i < 4; ++i){
      const int q = i * 256 + tid;
      const int r = q >> 3, cch = q & 7;
      const int sw = (cch ^ (r & 7)) << 3;
      const unsigned lofs = (unsigned)(i * 4096 + w * 1024);
      __builtin_amdgcn_global_load_lds(
          (const __attribute__((address_space(1))) void*)(A + (size_t)(m0 + r) * K + k0 + sw),
          (__attribute__((address_space(3))) void*)(sA + lofs), 16, 0, 0);
      __builtin_amdgcn_global_load_lds(
          (const __attribute__((address_space(1))) void*)(BT + (size_t)(n0 + r) * K + k0 + sw),
          (__attribute__((address_space(3))) void*)(sB + lofs), 16, 0, 0);
    }
    __syncthreads();
    #pragma unroll
    for (int s = 0; s < 2; ++s){
      s16x8 af[4], bfv[4];
      #pragma unroll
      for (int mi = 0; mi < 4; ++mi){
        const int r = wm * 64 + mi * 16 + (lane & 15);
        const int cg = s * 4 + (lane >> 4);
        af[mi] = *(const s16x8*)(sA + r * 128 + ((cg ^ (r & 7)) << 4));
      }
      #pragma unroll
      for (int ni = 0; ni < 4; ++ni){
        const int r = wn * 64 + ni * 16 + (lane & 15);
        const int cg = s * 4 + (lane >> 4);
        bfv[ni] = *(const s16x8*)(sB + r * 128 + ((cg ^ (r & 7)) << 4));
      }
      #pragma unroll
      for (int mi = 0; mi < 4; ++mi)
        #pragma unroll
        for (int ni = 0; ni < 4; ++ni)
          MFMA(acc[mi][ni], af[mi], bfv[ni]);
    }
    __syncthreads();
  }
  #pragma unroll
  for (int mi = 0; mi < 4; ++mi)
    #pragma unroll
    for (int ni = 0; ni < 4; ++ni)
      #pragma unroll
      for (int i = 0; i < 4; ++i){
        const int row = m0 + wm * 64 + mi * 16 + (lane >> 4) * 4 + i;
        const int col = n0 + wn * 64 + ni * 16 + (lane & 15);
        C[(size_t)row * N + col] = acc[mi][ni][i];
      }
}

// ---------------- fused RMSNorm + RoPE + split/cast ----------------
__global__ __launch_bounds__(256, 4) void k_rmsrope(const float* __restrict__ qkv,
    const float* __restrict__ cosT, const float* __restrict__ sinT,
    const float* __restrict__ qw, const float* __restrict__ kw,
    u16* __restrict__ qout, u16* __restrict__ kout, u16* __restrict__ vout){
  const int bs = blockIdx.x;
  const int b = bs >> 11, s = bs & 2047;
  const int lane = threadIdx.x & 63, w = threadIdx.x >> 6;
  const float* row = qkv + (size_t)bs * 4096;
  const float c1 = cosT[(size_t)bs * 128 + lane];
  const float s1 = sinT[(size_t)bs * 128 + lane];
  const float c2 = cosT[(size_t)bs * 128 + 64 + lane];
  const float s2 = sinT[(size_t)bs * 128 + 64 + lane];
  const float wq1 = qw[lane], wq2 = qw[64 + lane];
  const float wk1 = kw[lane], wk2 = kw[64 + lane];
  for (int u = w; u < 32; u += 4){
    if (u < 24){
      const int isq = (u < 16);
      const int base = isq ? u * 128 : 2048 + (u - 16) * 128;
      float x1 = row[base + lane], x2 = row[base + 64 + lane];
      float ss = x1 * x1 + x2 * x2;
      #pragma unroll
      for (int m = 1; m < 64; m <<= 1) ss += __shfl_xor(ss, m);
      float rsq = rsqrtf(ss * (1.0f / 128.0f) + 1e-6f);
      float n1 = x1 * rsq * (isq ? wq1 : wk1);
      float n2 = x2 * rsq * (isq ? wq2 : wk2);
      float o1 = n1 * c1 - n2 * s1;
      float o2 = n2 * c2 + n1 * s2;
      if (isq){
        size_t o = ((size_t)(b * 16 + u) * 2048 + s) * 128;
        qout[o + lane] = f2b(o1); qout[o + 64 + lane] = f2b(o2);
      } else {
        size_t o = ((size_t)(b * 8 + (u - 16)) * 2048 + s) * 128;
        kout[o + lane] = f2b(o1); kout[o + 64 + lane] = f2b(o2);
      }
    } else {
      const int j = u - 24;
      size_t o = ((size_t)(b * 8 + j) * 2048 + s) * 128;
      vout[o + lane] = f2b(row[3072 + j * 128 + lane]);
      vout[o + 64 + lane] = f2b(row[3072 + j * 128 + 64 + lane]);
    }
  }
}

// ---------------- flash attention v3 (causal, GQA 2:1) ----------------
// grid=1024: one 64-row q-tile per block, heavy-first (qt descending),
// bid%8 == kvh -> KV pinned to one XCD's L2. 4 blocks/CU (40KB LDS each).
// K: global_load_lds, XOR-swizzled.  V: global_load_lds into tr16-subtiled
// layout, PV B-frags via ds_read_b64_tr_b16 (waitcnt inside asm).
__global__ __launch_bounds__(256, 4) void k_attn(const u16* __restrict__ qb, const u16* __restrict__ kb,
                                                 const u16* __restrict__ vb, u16* __restrict__ ob){
  __shared__ __align__(128) u16 sK[64 * 128];   // [key][d], chunk-swizzled
  __shared__ __align__(128) u16 sV2[64 * 128];  // tr16-subtiled (see mapping)
  __shared__ __align__(128) u16 sP[4][16 * 64]; // per-wave [q][key], swizzled
  const int tid = threadIdx.x, lane = tid & 63, w = tid >> 6;
  const int bid = blockIdx.x;
  const int qt  = 31 - (bid >> 5);       // heavy q-tiles dispatched first
  const int s5  = bid & 31;
  const int kvh = s5 & 7;                // == bid%8 == XCD -> KV L2-pinned
  const int t2  = s5 >> 3;
  const int b   = t2 >> 1;
  const int h   = kvh * 2 + (t2 & 1);
  const u16* Q  = qb + ((size_t)(b * 16 + h)  * 2048) * 128;
  const u16* Kg = kb + ((size_t)(b * 8 + kvh) * 2048) * 128;
  const u16* Vg = vb + ((size_t)(b * 8 + kvh) * 2048) * 128;
  u16* sPw = sP[w];
  const unsigned vtr = (unsigned)(size_t)sV2 + lane * 8;  // low32 of flat = LDS offset

  const int qrow0 = qt * 64 + w * 16;
  s16x8 qf[4];
  #pragma unroll
  for (int kc = 0; kc < 4; ++kc)
    qf[kc] = *(const s16x8*)(Q + (size_t)(qrow0 + (lane & 15)) * 128 + kc * 32 + (lane >> 4) * 8);
  f32x4 acc[8] = {};
  float mx[4], lsum[4];
  #pragma unroll
  for (int i = 0; i < 4; ++i){ mx[i] = -1e30f; lsum[i] = 0.f; }

  const int nkt = qt + 1;
  for (int kt = 0; kt < nkt; ++kt){
    // ---- stage K (64x128), XOR-swizzled source ----
    #pragma unroll
    for (int i = 0; i < 4; ++i){
      const int q = i * 256 + tid;
      const int r = q >> 4, c = q & 15;
      const unsigned lofs = (unsigned)(i * 4096 + w * 1024);
      __builtin_amdgcn_global_load_lds(
          (const __attribute__((address_space(1))) void*)(Kg + (size_t)(kt * 64 + r) * 128 + ((c ^ (r & 7)) << 3)),
          (__attribute__((address_space(3))) void*)((char*)sK + lofs), 16, 0, 0);
    }
    // ---- stage V into tr16-subtiled layout ----
    // LDS elem(key,d) = ((d>>4)*16 + kst)*64 + (key&3)*16 + (d&15),
    // kst = (key>>5)*8 + ((key>>2)&1)*4 + ((key>>3)&3)
    #pragma unroll
    for (int i = 0; i < 4; ++i){
      const int q  = i * 256 + tid;
      const int st = q >> 3, w8 = q & 7;
      const int r  = w8 >> 1, hh = w8 & 1;
      const int dblk = st >> 4, kq = st & 15;
      const int key = (kq >> 3) * 32 + (kq & 3) * 8 + ((kq >> 2) & 1) * 4 + r;
      const int d   = dblk * 16 + hh * 8;
      const unsigned lofs = (unsigned)(i * 4096 + w * 1024);
      __builtin_amdgcn_global_load_lds(
          (const __attribute__((address_space(1))) void*)(Vg + (size_t)(kt * 64 + key) * 128 + d),
          (__attribute__((address_space(3))) void*)((char*)sV2 + lofs), 16, 0, 0);
    }
    __syncthreads();
    // ---- QK^T: 16 q-rows x 64 keys per wave ----
    f32x4 sc4[4] = {};
    #pragma unroll
    for (int nt = 0; nt < 4; ++nt)
      #pragma unroll
      for (int kc = 0; kc < 4; ++kc){
        s16x8 kf = *(const s16x8*)(sK + (nt * 16 + (lane & 15)) * 128 + (((kc * 4 + (lane >> 4)) ^ (lane & 7)) << 3));
        MFMA(sc4[nt], qf[kc], kf);
      }
    // ---- online softmax ----
    float p[4][4], rm[4];
    #pragma unroll
    for (int i = 0; i < 4; ++i) rm[i] = -1e30f;
    const int qbase = qrow0 + (lane >> 4) * 4;
    #pragma unroll
    for (int nt = 0; nt < 4; ++nt){
      const int key = kt * 64 + nt * 16 + (lane & 15);
      #pragma unroll
      for (int i = 0; i < 4; ++i){
        float v = sc4[nt][i] * 0.08838834764831845f;
        if (key > qbase + i) v = -1e30f;
        p[nt][i] = v;
        rm[i] = fmaxf(rm[i], v);
      }
    }
    #pragma unroll
    for (int m = 1; m < 16; m <<= 1)
      #pragma unroll
      for (int i = 0; i < 4; ++i) rm[i] = fmaxf(rm[i], __shfl_xor(rm[i], m));
    float alpha[4];
    #pragma unroll
    for (int i = 0; i < 4; ++i){
      float mn = fmaxf(mx[i], rm[i]);
      alpha[i] = __expf(mx[i] - mn);
      mx[i] = mn;
    }
    float rs[4] = {0.f, 0.f, 0.f, 0.f};
    #pragma unroll
    for (int nt = 0; nt < 4; ++nt)
      #pragma unroll
      for (int i = 0; i < 4; ++i){
        float e = __expf(p[nt][i] - mx[i]);
        p[nt][i] = e;
        rs[i] += e;
      }
    #pragma unroll
    for (int m = 1; m < 16; m <<= 1)
      #pragma unroll
      for (int i = 0; i < 4; ++i) rs[i] += __shfl_xor(rs[i], m);
    #pragma unroll
    for (int i = 0; i < 4; ++i) lsum[i] = lsum[i] * alpha[i] + rs[i];
    // ---- P -> per-wave LDS (swizzled; wave-private, no barrier) ----
    #pragma unroll
    for (int nt = 0; nt < 4; ++nt)
      #pragma unroll
      for (int i = 0; i < 4; ++i){
        const int ql = (lane >> 4) * 4 + i;
        const int kl = nt * 16 + (lane & 15);
        sPw[ql * 64 + (((kl >> 3) ^ (ql & 7)) << 3) + (kl & 7)] = f2b(p[nt][i]);
      }
    // ---- rescale + PV (B-frags via ds_read_b64_tr_b16) ----
    #pragma unroll
    for (int c = 0; c < 8; ++c)
      #pragma unroll
      for (int i = 0; i < 4; ++i) acc[c][i] *= alpha[i];
    s16x8 pf[2];
    #pragma unroll
    for (int ks = 0; ks < 2; ++ks)
      pf[ks] = *(const s16x8*)(sPw + (lane & 15) * 64 + (((ks * 4 + (lane >> 4)) ^ (lane & 7)) << 3));
    #pragma unroll
    for (int cc = 0; cc < 8; cc += 2){
      s16x4 a0, a1, a2, a3, b0, b1, b2, b3;
      const unsigned va = vtr + (unsigned)(cc * 2048);
      asm volatile(
        "ds_read_b64_tr_b16 %0, %8\n\t"
        "ds_read_b64_tr_b16 %1, %8 offset:512\n\t"
        "ds_read_b64_tr_b16 %2, %8 offset:1024\n\t"
        "ds_read_b64_tr_b16 %3, %8 offset:1536\n\t"
        "ds_read_b64_tr_b16 %4, %8 offset:2048\n\t"
        "ds_read_b64_tr_b16 %5, %8 offset:2560\n\t"
        "ds_read_b64_tr_b16 %6, %8 offset:3072\n\t"
        "ds_read_b64_tr_b16 %7, %8 offset:3584\n\t"
        "s_waitcnt lgkmcnt(0)"
        : "=&v"(a0), "=&v"(a1), "=&v"(a2), "=&v"(a3),
          "=&v"(b0), "=&v"(b1), "=&v"(b2), "=&v"(b3)
        : "v"(va));
      MFMA(acc[cc],     pf[0], cat8(a0, a1));
      MFMA(acc[cc],     pf[1], cat8(a2, a3));
      MFMA(acc[cc + 1], pf[0], cat8(b0, b1));
      MFMA(acc[cc + 1], pf[1], cat8(b2, b3));
    }
    __syncthreads();
  }
  // ---- epilogue ----
  #pragma unroll
  for (int c = 0; c < 8; ++c)
    #pragma unroll
    for (int i = 0; i < 4; ++i){
      const int row = qrow0 + (lane >> 4) * 4 + i;
      const int col = h * 128 + c * 16 + (lane & 15);
      ob[((size_t)(b * 2048) + row) * 2048 + col] = f2b(acc[c][i] / lsum[i]);
    }
}

extern "C" void kernel_launch(void* const* d_in, const int* in_sizes, int n_in,
                              void* d_out, int out_size, void* d_ws, size_t ws_size,
                              hipStream_t stream){
  const float* hs   = (const float*)d_in[0];
  const float* cosT = (const float*)d_in[1];
  const float* sinT = (const float*)d_in[2];
  const float* Wq = (const float*)d_in[4];
  const float* Wk = (const float*)d_in[5];
  const float* Wv = (const float*)d_in[6];
  const float* Wo = (const float*)d_in[7];
  const float* qw = (const float*)d_in[8];
  const float* kw = (const float*)d_in[9];
  float* out = (float*)d_out;
  char* ws = (char*)d_ws;

  u16*   hsb   = (u16*)(ws);                         // 16 MB  (later: q bf16)
  u16*   wqkvT = (u16*)(ws + 16777216);              // 16 MB  (later: k,v bf16)
  u16*   woT   = (u16*)(ws + 33554432);              // 8 MB
  float* qkv   = (float*)(ws + 41943040);            // 64 MB  (later: attn out bf16)
  u16*   qb    = hsb;
  u16*   kb2   = (u16*)(ws + 16777216);
  u16*   vb2   = (u16*)(ws + 16777216 + 8388608);
  u16*   attnb = (u16*)(ws + 41943040);

  k_cast<<<4096, 256, 0, stream>>>(hs, hsb, 1048576);
  k_transpose<<<dim3(64, 64),  256, 0, stream>>>(Wq, wqkvT,                       2048, 2048);
  k_transpose<<<dim3(32, 64),  256, 0, stream>>>(Wk, wqkvT + (size_t)2048 * 2048, 2048, 1024);
  k_transpose<<<dim3(32, 64),  256, 0, stream>>>(Wv, wqkvT + (size_t)3072 * 2048, 2048, 1024);
  k_transpose<<<dim3(64, 64),  256, 0, stream>>>(Wo, woT,                         2048, 2048);
  k_gemm<<<dim3(32, 32), 256, 0, stream>>>(hsb, wqkvT, qkv, 4096, 4096, 2048);
  k_rmsrope<<<4096, 256, 0, stream>>>(qkv, cosT, sinT, qw, kw, qb, kb2, vb2);
  k_attn<<<1024, 256, 0, stream>>>(qb, kb2, vb2, attnb);
  k_gemm<<<dim3(16, 32), 256, 0, stream>>>(attnb, woT, out, 4096, 2048, 2048);
}

// Round 5
// 238.383 us; speedup vs baseline: 1.7436x; 1.1510x over previous
//
#include <hip/hip_runtime.h>

typedef unsigned short u16;
typedef unsigned short u16x8 __attribute__((ext_vector_type(8)));
typedef short s16x8 __attribute__((ext_vector_type(8)));
typedef float f32x4 __attribute__((ext_vector_type(4)));
typedef float f32x16 __attribute__((ext_vector_type(16)));
typedef unsigned u32x4 __attribute__((ext_vector_type(4)));

__device__ __forceinline__ u16 f2b(float f){
  unsigned u = __builtin_bit_cast(unsigned, f);
  u += 0x7fffu + ((u >> 16) & 1u);
  return (u16)(u >> 16);
}

#define MFMA16(c, a, b) (c) = __builtin_amdgcn_mfma_f32_16x16x32_bf16((a), (b), (c), 0, 0, 0)
#define MFMA32(c, a, b) (c) = __builtin_amdgcn_mfma_f32_32x32x16_bf16((a), (b), (c), 0, 0, 0)

// ---------------- cast hidden_states f32 -> bf16 ----------------
__global__ void k_cast(const float* __restrict__ src, u16* __restrict__ dst, int n8){
  int i = blockIdx.x * blockDim.x + threadIdx.x;
  if (i >= n8) return;
  const float4* s = (const float4*)(src + (size_t)i * 8);
  float4 a = s[0], b = s[1];
  u16x8 o;
  o[0]=f2b(a.x); o[1]=f2b(a.y); o[2]=f2b(a.z); o[3]=f2b(a.w);
  o[4]=f2b(b.x); o[5]=f2b(b.y); o[6]=f2b(b.z); o[7]=f2b(b.w);
  *(u16x8*)(dst + (size_t)i * 8) = o;
}

// ------- transpose+cast: src (K x N f32) -> dst (N x K bf16) -------
__global__ void k_transpose(const float* __restrict__ src, u16* __restrict__ dst, int K, int N){
  __shared__ float t[32][33];
  int n0 = blockIdx.x * 32, k0 = blockIdx.y * 32;
  int c = threadIdx.x & 31, r4 = threadIdx.x >> 5;
  #pragma unroll
  for (int p = 0; p < 4; ++p){
    int r = r4 + p * 8;
    t[r][c] = src[(size_t)(k0 + r) * N + n0 + c];
  }
  __syncthreads();
  #pragma unroll
  for (int p = 0; p < 4; ++p){
    int r = r4 + p * 8;
    dst[(size_t)(n0 + r) * K + k0 + c] = f2b(t[c][r]);
  }
}

// ---------------- GEMM: C(MxN,f32) = A(MxK,bf16) * BT(NxK,bf16)^T ----------------
__global__ __launch_bounds__(256, 2) void k_gemm(const u16* __restrict__ A, const u16* __restrict__ BT,
                                                 float* __restrict__ C, int M, int N, int K){
  __shared__ __align__(16) char sm[32768];
  char* sA = sm;
  char* sB = sm + 16384;
  const int tid = threadIdx.x;
  const int lane = tid & 63, w = tid >> 6;
  const int wm = w >> 1, wn = w & 1;
  const int m0 = blockIdx.y * 128, n0 = blockIdx.x * 128;
  f32x4 acc[4][4] = {};
  const int nk = K >> 6;
  for (int kt = 0; kt < nk; ++kt){
    const int k0 = kt << 6;
    #pragma unroll
    for (int i = 0; i < 4; ++i){
      const int q = i * 256 + tid;
      const int r = q >> 3, cch = q & 7;
      const int sw = (cch ^ (r & 7)) << 3;
      const unsigned lofs = (unsigned)(i * 4096 + w * 1024);
      __builtin_amdgcn_global_load_lds(
          (const __attribute__((address_space(1))) void*)(A + (size_t)(m0 + r) * K + k0 + sw),
          (__attribute__((address_space(3))) void*)(sA + lofs), 16, 0, 0);
      __builtin_amdgcn_global_load_lds(
          (const __attribute__((address_space(1))) void*)(BT + (size_t)(n0 + r) * K + k0 + sw),
          (__attribute__((address_space(3))) void*)(sB + lofs), 16, 0, 0);
    }
    __syncthreads();
    #pragma unroll
    for (int s = 0; s < 2; ++s){
      s16x8 af[4], bfv[4];
      #pragma unroll
      for (int mi = 0; mi < 4; ++mi){
        const int r = wm * 64 + mi * 16 + (lane & 15);
        const int cg = s * 4 + (lane >> 4);
        af[mi] = *(const s16x8*)(sA + r * 128 + ((cg ^ (r & 7)) << 4));
      }
      #pragma unroll
      for (int ni = 0; ni < 4; ++ni){
        const int r = wn * 64 + ni * 16 + (lane & 15);
        const int cg = s * 4 + (lane >> 4);
        bfv[ni] = *(const s16x8*)(sB + r * 128 + ((cg ^ (r & 7)) << 4));
      }
      #pragma unroll
      for (int mi = 0; mi < 4; ++mi)
        #pragma unroll
        for (int ni = 0; ni < 4; ++ni)
          MFMA16(acc[mi][ni], af[mi], bfv[ni]);
    }
    __syncthreads();
  }
  #pragma unroll
  for (int mi = 0; mi < 4; ++mi)
    #pragma unroll
    for (int ni = 0; ni < 4; ++ni)
      #pragma unroll
      for (int i = 0; i < 4; ++i){
        const int row = m0 + wm * 64 + mi * 16 + (lane >> 4) * 4 + i;
        const int col = n0 + wn * 64 + ni * 16 + (lane & 15);
        C[(size_t)row * N + col] = acc[mi][ni][i];
      }
}

// ---------------- fused RMSNorm + RoPE + split/cast ----------------
__global__ __launch_bounds__(256, 4) void k_rmsrope(const float* __restrict__ qkv,
    const float* __restrict__ cosT, const float* __restrict__ sinT,
    const float* __restrict__ qw, const float* __restrict__ kw,
    u16* __restrict__ qout, u16* __restrict__ kout, u16* __restrict__ vout){
  const int bs = blockIdx.x;
  const int b = bs >> 11, s = bs & 2047;
  const int lane = threadIdx.x & 63, w = threadIdx.x >> 6;
  const float* row = qkv + (size_t)bs * 4096;
  const float c1 = cosT[(size_t)bs * 128 + lane];
  const float s1 = sinT[(size_t)bs * 128 + lane];
  const float c2 = cosT[(size_t)bs * 128 + 64 + lane];
  const float s2 = sinT[(size_t)bs * 128 + 64 + lane];
  const float wq1 = qw[lane], wq2 = qw[64 + lane];
  const float wk1 = kw[lane], wk2 = kw[64 + lane];
  for (int u = w; u < 32; u += 4){
    if (u < 24){
      const int isq = (u < 16);
      const int base = isq ? u * 128 : 2048 + (u - 16) * 128;
      float x1 = row[base + lane], x2 = row[base + 64 + lane];
      float ss = x1 * x1 + x2 * x2;
      #pragma unroll
      for (int m = 1; m < 64; m <<= 1) ss += __shfl_xor(ss, m);
      float rsq = rsqrtf(ss * (1.0f / 128.0f) + 1e-6f);
      float n1 = x1 * rsq * (isq ? wq1 : wk1);
      float n2 = x2 * rsq * (isq ? wq2 : wk2);
      float o1 = n1 * c1 - n2 * s1;
      float o2 = n2 * c2 + n1 * s2;
      if (isq){
        size_t o = ((size_t)(b * 16 + u) * 2048 + s) * 128;
        qout[o + lane] = f2b(o1); qout[o + 64 + lane] = f2b(o2);
      } else {
        size_t o = ((size_t)(b * 8 + (u - 16)) * 2048 + s) * 128;
        kout[o + lane] = f2b(o1); kout[o + 64 + lane] = f2b(o2);
      }
    } else {
      const int j = u - 24;
      size_t o = ((size_t)(b * 8 + j) * 2048 + s) * 128;
      vout[o + lane] = f2b(row[3072 + j * 128 + lane]);
      vout[o + 64 + lane] = f2b(row[3072 + j * 128 + 64 + lane]);
    }
  }
}

// ---------------- V transpose: [bh][s][d] -> [bh][d][s] (bf16) ----------------
__global__ __launch_bounds__(256, 8) void k_vtrans(const u16* __restrict__ v, u16* __restrict__ vt){
  __shared__ u16 t[64][130];
  const int bid = blockIdx.x;
  const int hd = bid >> 5, sb = bid & 31;
  const u16* src = v + (size_t)hd * 262144 + (size_t)sb * 64 * 128;
  u16* dst = vt + (size_t)hd * 262144 + sb * 64;
  const int tid = threadIdx.x;
  const int r = tid >> 2, c0 = (tid & 3) * 32;
  #pragma unroll
  for (int j = 0; j < 4; ++j)
    *(u16x8*)&t[r][c0 + j * 8] = *(const u16x8*)(src + r * 128 + c0 + j * 8);
  __syncthreads();
  const int d = tid >> 1, s0 = (tid & 1) * 32;
  #pragma unroll
  for (int j = 0; j < 4; ++j){
    u16x8 ov;
    #pragma unroll
    for (int e = 0; e < 8; ++e) ov[e] = t[s0 + j * 8 + e][d];
    *(u16x8*)(dst + (size_t)d * 2048 + s0 + j * 8) = ov;
  }
}

// ---------------- flash attention v4: 32x32 MFMA, swapped QK, in-reg softmax ----------------
// grid=512: slot=bid>>5 -> qt via anti-paired seq (co-resident blocks sum to 17 units);
// bh=bid&31, kvh=bid&7 (XCD-pinned KV). 4 waves x 32 q-rows = 128-row q-tile.
// K LDS [key][d] chunk16-XOR-swizzled; V LDS [d][key] chunk16-XOR-swizzled (from pre-transposed Vt).
// Double-buffered, counted vmcnt(8), raw barriers. P stays in registers (cvt_pk + permlane32_swap).
__device__ __forceinline__ void stage_kv(const u16* __restrict__ Kg, const u16* __restrict__ Vt,
                                         int kt, u16* sKb, u16* sVb, int tid){
  #pragma unroll
  for (int i = 0; i < 4; ++i){
    const int off = i * 4096 + tid * 16;           // byte offset (linear LDS dest)
    const unsigned wub = (unsigned)(i * 4096 + (tid >> 6) * 1024); // wave-uniform base
    const int key = off >> 8, ks = (off >> 4) & 15;
    __builtin_amdgcn_global_load_lds(
        (const __attribute__((address_space(1))) void*)(Kg + (size_t)(kt * 64 + key) * 128 + ((ks ^ (key & 15)) << 3)),
        (__attribute__((address_space(3))) void*)((char*)sKb + wub), 16, 0, 0);
    const int d = off >> 7, vs = (off >> 4) & 7;
    __builtin_amdgcn_global_load_lds(
        (const __attribute__((address_space(1))) void*)(Vt + (size_t)d * 2048 + kt * 64 + ((vs ^ (d & 7)) << 3)),
        (__attribute__((address_space(3))) void*)((char*)sVb + wub), 16, 0, 0);
  }
}

__global__ __launch_bounds__(256, 2) void k_attn(const u16* __restrict__ qb, const u16* __restrict__ kb,
                                                 const u16* __restrict__ vtb, u16* __restrict__ ob){
  __shared__ __align__(128) u16 sK[2][64 * 128];
  __shared__ __align__(128) u16 sV[2][128 * 64];
  const int tid = threadIdx.x, lane = tid & 63, w = tid >> 6;
  const int hi = lane >> 5, l31 = lane & 31;
  const int bid = blockIdx.x;
  const int bh = bid & 31;
  const int kvh = bh & 7, r2 = bh >> 3;
  const int b = r2 >> 1, h = kvh * 2 + (r2 & 1);
  const int slot = bid >> 5;
  const int qt = (slot < 8) ? (15 - 2 * slot) : (2 * slot - 16);  // anti-paired order
  const u16* Q  = qb  + ((size_t)(b * 16 + h)  * 2048) * 128;
  const u16* Kg = kb  + ((size_t)(b * 8 + kvh) * 2048) * 128;
  const u16* Vt = vtb + ((size_t)(b * 8 + kvh) * 128) * 2048;
  const int qrow0 = qt * 128 + w * 32;

  s16x8 qf[8];
  #pragma unroll
  for (int ds = 0; ds < 8; ++ds)
    qf[ds] = *(const s16x8*)(Q + (size_t)(qrow0 + l31) * 128 + ds * 16 + hi * 8);

  f32x16 acc[4] = {};
  float mx = -1e30f, lsum = 0.f;
  const int nkt = qt * 2 + 2;

  stage_kv(Kg, Vt, 0, sK[0], sV[0], tid);
  for (int kt = 0; kt < nkt; ++kt){
    const int cur = kt & 1;
    if (kt + 1 < nkt){
      stage_kv(Kg, Vt, kt + 1, sK[cur ^ 1], sV[cur ^ 1], tid);
      asm volatile("s_waitcnt vmcnt(8)");
    } else {
      asm volatile("s_waitcnt vmcnt(0)");
    }
    __builtin_amdgcn_s_barrier();

    if (kt * 64 <= qrow0 + 31){   // wave-uniform: skip fully-masked waves
      const char* sKc = (const char*)sK[cur];
      const char* sVc = (const char*)sV[cur];
      // ---- QK^T (swapped): sc[kb] cols=q, rows=keys ----
      f32x16 s0 = {}, s1 = {};
      #pragma unroll
      for (int ds = 0; ds < 8; ++ds){
        const int sl = ((ds * 2 + hi) ^ (l31 & 15)) << 4;
        s16x8 k0 = *(const s16x8*)(sKc + l31 * 256 + sl);
        s16x8 k1 = *(const s16x8*)(sKc + 8192 + l31 * 256 + sl);
        MFMA32(s0, k0, qf[ds]);
        MFMA32(s1, k1, qf[ds]);
      }
      // ---- scale + causal mask + tile max ----
      const int qg = qrow0 + l31;
      const bool domask = (kt * 64 + 63) > qrow0;
      float pv0[16], pv1[16];
      float pmax = -1e30f;
      #pragma unroll
      for (int r = 0; r < 16; ++r){
        const int krow = (r & 3) + 8 * (r >> 2) + 4 * hi;
        float v0 = s0[r] * 0.08838834764831845f;
        float v1 = s1[r] * 0.08838834764831845f;
        if (domask){
          if (kt * 64 + krow > qg)      v0 = -1e30f;
          if (kt * 64 + 32 + krow > qg) v1 = -1e30f;
        }
        pv0[r] = v0; pv1[r] = v1;
        pmax = fmaxf(pmax, fmaxf(v0, v1));
      }
      pmax = fmaxf(pmax, __shfl_xor(pmax, 32));
      // ---- defer-max (T13): rescale only on significant growth ----
      if (!__all(pmax - mx <= 8.f)){
        const float mn = fmaxf(mx, pmax);
        const float al = __expf(mx - mn);
        mx = mn; lsum *= al;
        #pragma unroll
        for (int r = 0; r < 16; ++r){
          const float ar = __shfl(al, (r & 3) + 8 * (r >> 2) + 4 * hi);
          acc[0][r] *= ar; acc[1][r] *= ar; acc[2][r] *= ar; acc[3][r] *= ar;
        }
      }
      float rs = 0.f;
      #pragma unroll
      for (int r = 0; r < 16; ++r){
        const float e0 = __expf(pv0[r] - mx);
        const float e1 = __expf(pv1[r] - mx);
        pv0[r] = e0; pv1[r] = e1;
        rs += e0 + e1;
      }
      rs += __shfl_xor(rs, 32);
      lsum += rs;
      // ---- P pack (cvt_pk + permlane32_swap) + PV ----
      #pragma unroll
      for (int s = 0; s < 4; ++s){
        const int t8 = (s & 1) * 8;
        unsigned w0, w1, w2, w3;
        if (s < 2){
          asm("v_cvt_pk_bf16_f32 %0, %1, %2" : "=v"(w0) : "v"(pv0[t8+0]), "v"(pv0[t8+1]));
          asm("v_cvt_pk_bf16_f32 %0, %1, %2" : "=v"(w1) : "v"(pv0[t8+2]), "v"(pv0[t8+3]));
          asm("v_cvt_pk_bf16_f32 %0, %1, %2" : "=v"(w2) : "v"(pv0[t8+4]), "v"(pv0[t8+5]));
          asm("v_cvt_pk_bf16_f32 %0, %1, %2" : "=v"(w3) : "v"(pv0[t8+6]), "v"(pv0[t8+7]));
        } else {
          asm("v_cvt_pk_bf16_f32 %0, %1, %2" : "=v"(w0) : "v"(pv1[t8+0]), "v"(pv1[t8+1]));
          asm("v_cvt_pk_bf16_f32 %0, %1, %2" : "=v"(w1) : "v"(pv1[t8+2]), "v"(pv1[t8+3]));
          asm("v_cvt_pk_bf16_f32 %0, %1, %2" : "=v"(w2) : "v"(pv1[t8+4]), "v"(pv1[t8+5]));
          asm("v_cvt_pk_bf16_f32 %0, %1, %2" : "=v"(w3) : "v"(pv1[t8+6]), "v"(pv1[t8+7]));
        }
        asm("v_permlane32_swap_b32 %0, %1" : "+v"(w0), "+v"(w2));
        asm("v_permlane32_swap_b32 %0, %1" : "+v"(w1), "+v"(w3));
        u32x4 pw = {w0, w1, w2, w3};
        s16x8 pa = __builtin_bit_cast(s16x8, pw);
        #pragma unroll
        for (int db = 0; db < 4; ++db){
          const int d = db * 32 + l31;
          s16x8 vf = *(const s16x8*)(sVc + d * 128 + (((s * 2 + hi) ^ (d & 7)) << 4));
          MFMA32(acc[db], pa, vf);
        }
      }
    }
    asm volatile("s_waitcnt lgkmcnt(0)");
    __builtin_amdgcn_s_barrier();
  }
  // ---- epilogue: O/l -> (B,S,H*HD) bf16 ----
  float li[16];
  #pragma unroll
  for (int r = 0; r < 16; ++r)
    li[r] = __shfl(lsum, (r & 3) + 8 * (r >> 2) + 4 * hi);
  #pragma unroll
  for (int db = 0; db < 4; ++db)
    #pragma unroll
    for (int r = 0; r < 16; ++r){
      const int row = qrow0 + (r & 3) + 8 * (r >> 2) + 4 * hi;
      const int col = h * 128 + db * 32 + l31;
      ob[((size_t)(b * 2048) + row) * 2048 + col] = f2b(acc[db][r] / li[r]);
    }
}

extern "C" void kernel_launch(void* const* d_in, const int* in_sizes, int n_in,
                              void* d_out, int out_size, void* d_ws, size_t ws_size,
                              hipStream_t stream){
  const float* hs   = (const float*)d_in[0];
  const float* cosT = (const float*)d_in[1];
  const float* sinT = (const float*)d_in[2];
  const float* Wq = (const float*)d_in[4];
  const float* Wk = (const float*)d_in[5];
  const float* Wv = (const float*)d_in[6];
  const float* Wo = (const float*)d_in[7];
  const float* qw = (const float*)d_in[8];
  const float* kw = (const float*)d_in[9];
  float* out = (float*)d_out;
  char* ws = (char*)d_ws;

  u16*   hsb   = (u16*)(ws);                         // 16 MB (later: q bf16)
  u16*   wqkvT = (u16*)(ws + 16777216);              // 16 MB (later: k,v bf16)
  u16*   woT   = (u16*)(ws + 33554432);              // 8 MB
  float* qkv   = (float*)(ws + 41943040);            // 64 MB fp32 (freed after rmsrope)
  u16*   qb    = hsb;
  u16*   kb2   = (u16*)(ws + 16777216);
  u16*   vb2   = (u16*)(ws + 16777216 + 8388608);
  u16*   attnb = (u16*)(ws + 41943040);              // 16 MB (aliases dead qkv)
  u16*   vtb   = (u16*)(ws + 41943040 + 16777216);   // 8 MB  (aliases dead qkv)

  k_cast<<<4096, 256, 0, stream>>>(hs, hsb, 1048576);
  k_transpose<<<dim3(64, 64),  256, 0, stream>>>(Wq, wqkvT,                       2048, 2048);
  k_transpose<<<dim3(32, 64),  256, 0, stream>>>(Wk, wqkvT + (size_t)2048 * 2048, 2048, 1024);
  k_transpose<<<dim3(32, 64),  256, 0, stream>>>(Wv, wqkvT + (size_t)3072 * 2048, 2048, 1024);
  k_transpose<<<dim3(64, 64),  256, 0, stream>>>(Wo, woT,                         2048, 2048);
  k_gemm<<<dim3(32, 32), 256, 0, stream>>>(hsb, wqkvT, qkv, 4096, 4096, 2048);
  k_rmsrope<<<4096, 256, 0, stream>>>(qkv, cosT, sinT, qw, kw, qb, kb2, vb2);
  k_vtrans<<<512, 256, 0, stream>>>(vb2, vtb);
  k_attn<<<512, 256, 0, stream>>>(qb, kb2, vtb, attnb);
  k_gemm<<<dim3(16, 32), 256, 0, stream>>>(attnb, woT, out, 4096, 2048, 2048);
}

// Round 6
// 228.245 us; speedup vs baseline: 1.8211x; 1.0444x over previous
//
#include <hip/hip_runtime.h>

typedef unsigned short u16;
typedef unsigned short u16x8 __attribute__((ext_vector_type(8)));
typedef short s16x8 __attribute__((ext_vector_type(8)));
typedef float f32x4 __attribute__((ext_vector_type(4)));
typedef float f32x16 __attribute__((ext_vector_type(16)));
typedef unsigned u32x4 __attribute__((ext_vector_type(4)));

__device__ __forceinline__ u16 f2b(float f){
  unsigned u = __builtin_bit_cast(unsigned, f);
  u += 0x7fffu + ((u >> 16) & 1u);
  return (u16)(u >> 16);
}
__device__ __forceinline__ float b2f(u16 v){
  unsigned u = ((unsigned)v) << 16;
  return __builtin_bit_cast(float, u);
}

#define MFMA16(c, a, b) (c) = __builtin_amdgcn_mfma_f32_16x16x32_bf16((a), (b), (c), 0, 0, 0)
#define MFMA32(c, a, b) (c) = __builtin_amdgcn_mfma_f32_32x32x16_bf16((a), (b), (c), 0, 0, 0)

__device__ __forceinline__ void gl16(const u16* g, char* l){
  __builtin_amdgcn_global_load_lds((const __attribute__((address_space(1))) void*)g,
                                   (__attribute__((address_space(3))) void*)l, 16, 0, 0);
}

// ---------------- cast hidden_states f32 -> bf16 ----------------
__global__ void k_cast(const float* __restrict__ src, u16* __restrict__ dst, int n8){
  int i = blockIdx.x * blockDim.x + threadIdx.x;
  if (i >= n8) return;
  const float4* s = (const float4*)(src + (size_t)i * 8);
  float4 a = s[0], b = s[1];
  u16x8 o;
  o[0]=f2b(a.x); o[1]=f2b(a.y); o[2]=f2b(a.z); o[3]=f2b(a.w);
  o[4]=f2b(b.x); o[5]=f2b(b.y); o[6]=f2b(b.z); o[7]=f2b(b.w);
  *(u16x8*)(dst + (size_t)i * 8) = o;
}

// ------- transpose+cast: src (K x N f32) -> dst (N x K bf16) -------
__global__ void k_transpose(const float* __restrict__ src, u16* __restrict__ dst, int K, int N){
  __shared__ float t[32][33];
  int n0 = blockIdx.x * 32, k0 = blockIdx.y * 32;
  int c = threadIdx.x & 31, r4 = threadIdx.x >> 5;
  #pragma unroll
  for (int p = 0; p < 4; ++p){
    int r = r4 + p * 8;
    t[r][c] = src[(size_t)(k0 + r) * N + n0 + c];
  }
  __syncthreads();
  #pragma unroll
  for (int p = 0; p < 4; ++p){
    int r = r4 + p * 8;
    dst[(size_t)(n0 + r) * K + k0 + c] = f2b(t[c][r]);
  }
}

// ---------------- 8-phase GEMM: C = A(MxK) * BT(NxK)^T ----------------
// BM=256, BN=NREP*64, BK=64, 8 waves (2M x 4N), per-wave 128 x NREP*16.
// Double-buffered LDS, 4 phases/K-tile, counted vmcnt (never 0 in loop),
// chunk-XOR swizzle both-sides (pre-swizzled global source + swizzled ds_read).
template<int NREP, bool OBF>
__global__ __launch_bounds__(512, 1) void k_gemm8(const u16* __restrict__ A, const u16* __restrict__ BT,
                                                  void* __restrict__ Cv, int M, int N, int K){
  constexpr int NH = NREP / 2;                 // n-frags per quadrant
  constexpr int BROWS = NREP * 32;             // B half rows: 128 (NREP=4) / 64 (NREP=2)
  constexpr int BLOADS = NREP / 2;             // B loads/thread/half: 2 or 1
  constexpr int TOT = 4 + 2 * BLOADS;          // loads/thread/K-tile: 8 or 6
  __shared__ __align__(16) u16 sA[2][2][128 * 64];
  __shared__ __align__(16) u16 sB[2][2][BROWS * 64];
  const int tid = threadIdx.x;
  const int lane = tid & 63, w = tid >> 6;
  const int l15 = lane & 15, l4 = lane >> 4;
  const int sx = l15 & 7;
  const int wr = w >> 2, wc = w & 3;
  const int m0 = blockIdx.y * 256, n0 = blockIdx.x * (NREP * 64);
  const int nk = K >> 6;

  f32x4 acc[8][NREP];
  #pragma unroll
  for (int mi = 0; mi < 8; ++mi)
    #pragma unroll
    for (int ni = 0; ni < NREP; ++ni) acc[mi][ni] = (f32x4){0.f, 0.f, 0.f, 0.f};

  // ---- staging helpers (linear LDS dest, pre-swizzled global source) ----
  auto stageA = [&](int d, int half, int k0){
    #pragma unroll
    for (int j = 0; j < 2; ++j){
      const int q = j * 512 + tid;
      const int r = q >> 3, cc = q & 7;
      gl16(A + (size_t)(m0 + half * 128 + r) * K + k0 + ((cc ^ (r & 7)) << 3),
           (char*)&sA[d][half][0] + j * 8192 + (tid >> 6) * 1024);
    }
  };
  auto stageB = [&](int d, int half, int k0){
    #pragma unroll
    for (int j = 0; j < BLOADS; ++j){
      const int q = j * 512 + tid;
      const int r = q >> 3, cc = q & 7;
      gl16(BT + (size_t)(n0 + half * BROWS + r) * K + k0 + ((cc ^ (r & 7)) << 3),
           (char*)&sB[d][half][0] + j * 8192 + (tid >> 6) * 1024);
    }
  };

  // ---- prologue: stage K-tiles 0 and 1 ----
  stageA(0, 0, 0); stageA(0, 1, 0); stageB(0, 0, 0); stageB(0, 1, 0);
  stageA(1, 0, 64); stageA(1, 1, 64); stageB(1, 0, 64); stageB(1, 1, 64);
  if constexpr (TOT == 8) asm volatile("s_waitcnt vmcnt(8)" ::: "memory");
  else                    asm volatile("s_waitcnt vmcnt(6)" ::: "memory");
  __builtin_amdgcn_s_barrier();

  const int halfB = wc >> 1;
  const int rb0 = (wc & 1) * (NREP * 16);

  for (int kt = 0; kt < nk; ++kt){
    const int d = kt & 1;
    const bool pre = (kt + 2) < nk;
    const int k0n = (kt + 2) << 6;
    const char* hA = (const char*)&sA[d][wr][0];
    const char* hB = (const char*)&sB[d][halfB][0];
    s16x8 aa[4][2], bb0[NH][2], bb1[NH][2];

    // ---- ph1: A m0-3 + B lo; MFMA q(0,0) ----
    #pragma unroll
    for (int mi = 0; mi < 4; ++mi)
      #pragma unroll
      for (int kk = 0; kk < 2; ++kk)
        aa[mi][kk] = *(const s16x8*)(hA + (mi * 16 + l15) * 128 + (((kk * 4 + l4) ^ sx) << 4));
    #pragma unroll
    for (int ni = 0; ni < NH; ++ni)
      #pragma unroll
      for (int kk = 0; kk < 2; ++kk)
        bb0[ni][kk] = *(const s16x8*)(hB + (rb0 + ni * 16 + l15) * 128 + (((kk * 4 + l4) ^ sx) << 4));
    __builtin_amdgcn_s_setprio(1);
    #pragma unroll
    for (int mi = 0; mi < 4; ++mi)
      #pragma unroll
      for (int ni = 0; ni < NH; ++ni)
        #pragma unroll
        for (int kk = 0; kk < 2; ++kk)
          MFMA16(acc[mi][ni], aa[mi][kk], bb0[ni][kk]);
    __builtin_amdgcn_s_setprio(0);

    // ---- ph2: B hi; MFMA q(0,1) ----
    #pragma unroll
    for (int ni = 0; ni < NH; ++ni)
      #pragma unroll
      for (int kk = 0; kk < 2; ++kk)
        bb1[ni][kk] = *(const s16x8*)(hB + (rb0 + (NH + ni) * 16 + l15) * 128 + (((kk * 4 + l4) ^ sx) << 4));
    __builtin_amdgcn_s_setprio(1);
    #pragma unroll
    for (int mi = 0; mi < 4; ++mi)
      #pragma unroll
      for (int ni = 0; ni < NH; ++ni)
        #pragma unroll
        for (int kk = 0; kk < 2; ++kk)
          MFMA16(acc[mi][NH + ni], aa[mi][kk], bb1[ni][kk]);
    __builtin_amdgcn_s_setprio(0);
    __builtin_amdgcn_s_barrier();          // all B reads of buf d done

    // ---- ph3: A m4-7; issue stageB(kt+2); MFMA q(1,0) ----
    #pragma unroll
    for (int mi = 0; mi < 4; ++mi)
      #pragma unroll
      for (int kk = 0; kk < 2; ++kk)
        aa[mi][kk] = *(const s16x8*)(hA + ((mi + 4) * 16 + l15) * 128 + (((kk * 4 + l4) ^ sx) << 4));
    if (pre){ stageB(d, 0, k0n); stageB(d, 1, k0n); }
    __builtin_amdgcn_s_setprio(1);
    #pragma unroll
    for (int mi = 0; mi < 4; ++mi)
      #pragma unroll
      for (int ni = 0; ni < NH; ++ni)
        #pragma unroll
        for (int kk = 0; kk < 2; ++kk)
          MFMA16(acc[mi + 4][ni], aa[mi][kk], bb0[ni][kk]);
    __builtin_amdgcn_s_setprio(0);
    __builtin_amdgcn_s_barrier();          // all A reads of buf d done

    // ---- ph4: issue stageA(kt+2); MFMA q(1,1); counted vmcnt ----
    if (pre){ stageA(d, 0, k0n); stageA(d, 1, k0n); }
    __builtin_amdgcn_s_setprio(1);
    #pragma unroll
    for (int mi = 0; mi < 4; ++mi)
      #pragma unroll
      for (int ni = 0; ni < NH; ++ni)
        #pragma unroll
        for (int kk = 0; kk < 2; ++kk)
          MFMA16(acc[mi + 4][NH + ni], aa[mi][kk], bb1[ni][kk]);
    __builtin_amdgcn_s_setprio(0);
    if (kt + 1 < nk){
      if (pre){
        if constexpr (TOT == 8) asm volatile("s_waitcnt vmcnt(8)" ::: "memory");
        else                    asm volatile("s_waitcnt vmcnt(6)" ::: "memory");
      } else {
        asm volatile("s_waitcnt vmcnt(0)" ::: "memory");
      }
      __builtin_amdgcn_s_barrier();
    }
  }

  // ---- epilogue ----
  #pragma unroll
  for (int mi = 0; mi < 8; ++mi)
    #pragma unroll
    for (int ni = 0; ni < NREP; ++ni)
      #pragma unroll
      for (int i = 0; i < 4; ++i){
        const int row = m0 + wr * 128 + mi * 16 + l4 * 4 + i;
        const int col = n0 + wc * (NREP * 16) + ni * 16 + l15;
        if constexpr (OBF) ((u16*)Cv)[(size_t)row * N + col] = f2b(acc[mi][ni][i]);
        else               ((float*)Cv)[(size_t)row * N + col] = acc[mi][ni][i];
      }
}

// ---------------- fused RMSNorm + RoPE + split/cast (bf16 input) ----------------
__global__ __launch_bounds__(256, 4) void k_rmsrope(const u16* __restrict__ qkvb,
    const float* __restrict__ cosT, const float* __restrict__ sinT,
    const float* __restrict__ qw, const float* __restrict__ kw,
    u16* __restrict__ qout, u16* __restrict__ kout, u16* __restrict__ vout){
  const int bs = blockIdx.x;
  const int b = bs >> 11, s = bs & 2047;
  const int lane = threadIdx.x & 63, w = threadIdx.x >> 6;
  const u16* row = qkvb + (size_t)bs * 4096;
  const float c1 = cosT[(size_t)bs * 128 + lane];
  const float s1 = sinT[(size_t)bs * 128 + lane];
  const float c2 = cosT[(size_t)bs * 128 + 64 + lane];
  const float s2 = sinT[(size_t)bs * 128 + 64 + lane];
  const float wq1 = qw[lane], wq2 = qw[64 + lane];
  const float wk1 = kw[lane], wk2 = kw[64 + lane];
  for (int u = w; u < 32; u += 4){
    if (u < 24){
      const int isq = (u < 16);
      const int base = isq ? u * 128 : 2048 + (u - 16) * 128;
      float x1 = b2f(row[base + lane]), x2 = b2f(row[base + 64 + lane]);
      float ss = x1 * x1 + x2 * x2;
      #pragma unroll
      for (int m = 1; m < 64; m <<= 1) ss += __shfl_xor(ss, m);
      float rsq = rsqrtf(ss * (1.0f / 128.0f) + 1e-6f);
      float n1 = x1 * rsq * (isq ? wq1 : wk1);
      float n2 = x2 * rsq * (isq ? wq2 : wk2);
      float o1 = n1 * c1 - n2 * s1;
      float o2 = n2 * c2 + n1 * s2;
      if (isq){
        size_t o = ((size_t)(b * 16 + u) * 2048 + s) * 128;
        qout[o + lane] = f2b(o1); qout[o + 64 + lane] = f2b(o2);
      } else {
        size_t o = ((size_t)(b * 8 + (u - 16)) * 2048 + s) * 128;
        kout[o + lane] = f2b(o1); kout[o + 64 + lane] = f2b(o2);
      }
    } else {
      const int j = u - 24;
      size_t o = ((size_t)(b * 8 + j) * 2048 + s) * 128;
      vout[o + lane] = row[3072 + j * 128 + lane];
      vout[o + 64 + lane] = row[3072 + j * 128 + 64 + lane];
    }
  }
}

// ---------------- V transpose: [bh][s][d] -> [bh][d][s] (bf16) ----------------
__global__ __launch_bounds__(256, 8) void k_vtrans(const u16* __restrict__ v, u16* __restrict__ vt){
  __shared__ u16 t[64][130];
  const int bid = blockIdx.x;
  const int hd = bid >> 5, sb = bid & 31;
  const u16* src = v + (size_t)hd * 262144 + (size_t)sb * 64 * 128;
  u16* dst = vt + (size_t)hd * 262144 + sb * 64;
  const int tid = threadIdx.x;
  const int r = tid >> 2, c0 = (tid & 3) * 32;
  #pragma unroll
  for (int j = 0; j < 4; ++j)
    *(u16x8*)&t[r][c0 + j * 8] = *(const u16x8*)(src + r * 128 + c0 + j * 8);
  __syncthreads();
  const int d = tid >> 1, s0 = (tid & 1) * 32;
  #pragma unroll
  for (int j = 0; j < 4; ++j){
    u16x8 ov;
    #pragma unroll
    for (int e = 0; e < 8; ++e) ov[e] = t[s0 + j * 8 + e][d];
    *(u16x8*)(dst + (size_t)d * 2048 + s0 + j * 8) = ov;
  }
}

// ---------------- flash attention v4 (unchanged from round 5) ----------------
__device__ __forceinline__ void stage_kv(const u16* __restrict__ Kg, const u16* __restrict__ Vt,
                                         int kt, u16* sKb, u16* sVb, int tid){
  #pragma unroll
  for (int i = 0; i < 4; ++i){
    const int off = i * 4096 + tid * 16;
    const unsigned wub = (unsigned)(i * 4096 + (tid >> 6) * 1024);
    const int key = off >> 8, ks = (off >> 4) & 15;
    __builtin_amdgcn_global_load_lds(
        (const __attribute__((address_space(1))) void*)(Kg + (size_t)(kt * 64 + key) * 128 + ((ks ^ (key & 15)) << 3)),
        (__attribute__((address_space(3))) void*)((char*)sKb + wub), 16, 0, 0);
    const int d = off >> 7, vs = (off >> 4) & 7;
    __builtin_amdgcn_global_load_lds(
        (const __attribute__((address_space(1))) void*)(Vt + (size_t)d * 2048 + kt * 64 + ((vs ^ (d & 7)) << 3)),
        (__attribute__((address_space(3))) void*)((char*)sVb + wub), 16, 0, 0);
  }
}

__global__ __launch_bounds__(256, 2) void k_attn(const u16* __restrict__ qb, const u16* __restrict__ kb,
                                                 const u16* __restrict__ vtb, u16* __restrict__ ob){
  __shared__ __align__(128) u16 sK[2][64 * 128];
  __shared__ __align__(128) u16 sV[2][128 * 64];
  const int tid = threadIdx.x, lane = tid & 63, w = tid >> 6;
  const int hi = lane >> 5, l31 = lane & 31;
  const int bid = blockIdx.x;
  const int bh = bid & 31;
  const int kvh = bh & 7, r2 = bh >> 3;
  const int b = r2 >> 1, h = kvh * 2 + (r2 & 1);
  const int slot = bid >> 5;
  const int qt = (slot < 8) ? (15 - 2 * slot) : (2 * slot - 16);
  const u16* Q  = qb  + ((size_t)(b * 16 + h)  * 2048) * 128;
  const u16* Kg = kb  + ((size_t)(b * 8 + kvh) * 2048) * 128;
  const u16* Vt = vtb + ((size_t)(b * 8 + kvh) * 128) * 2048;
  const int qrow0 = qt * 128 + w * 32;

  s16x8 qf[8];
  #pragma unroll
  for (int ds = 0; ds < 8; ++ds)
    qf[ds] = *(const s16x8*)(Q + (size_t)(qrow0 + l31) * 128 + ds * 16 + hi * 8);

  f32x16 acc[4] = {};
  float mx = -1e30f, lsum = 0.f;
  const int nkt = qt * 2 + 2;

  stage_kv(Kg, Vt, 0, sK[0], sV[0], tid);
  for (int kt = 0; kt < nkt; ++kt){
    const int cur = kt & 1;
    if (kt + 1 < nkt){
      stage_kv(Kg, Vt, kt + 1, sK[cur ^ 1], sV[cur ^ 1], tid);
      asm volatile("s_waitcnt vmcnt(8)");
    } else {
      asm volatile("s_waitcnt vmcnt(0)");
    }
    __builtin_amdgcn_s_barrier();

    if (kt * 64 <= qrow0 + 31){
      const char* sKc = (const char*)sK[cur];
      const char* sVc = (const char*)sV[cur];
      f32x16 s0 = {}, s1 = {};
      #pragma unroll
      for (int ds = 0; ds < 8; ++ds){
        const int sl = ((ds * 2 + hi) ^ (l31 & 15)) << 4;
        s16x8 k0 = *(const s16x8*)(sKc + l31 * 256 + sl);
        s16x8 k1 = *(const s16x8*)(sKc + 8192 + l31 * 256 + sl);
        MFMA32(s0, k0, qf[ds]);
        MFMA32(s1, k1, qf[ds]);
      }
      const int qg = qrow0 + l31;
      const bool domask = (kt * 64 + 63) > qrow0;
      float pv0[16], pv1[16];
      float pmax = -1e30f;
      #pragma unroll
      for (int r = 0; r < 16; ++r){
        const int krow = (r & 3) + 8 * (r >> 2) + 4 * hi;
        float v0 = s0[r] * 0.08838834764831845f;
        float v1 = s1[r] * 0.08838834764831845f;
        if (domask){
          if (kt * 64 + krow > qg)      v0 = -1e30f;
          if (kt * 64 + 32 + krow > qg) v1 = -1e30f;
        }
        pv0[r] = v0; pv1[r] = v1;
        pmax = fmaxf(pmax, fmaxf(v0, v1));
      }
      pmax = fmaxf(pmax, __shfl_xor(pmax, 32));
      if (!__all(pmax - mx <= 8.f)){
        const float mn = fmaxf(mx, pmax);
        const float al = __expf(mx - mn);
        mx = mn; lsum *= al;
        #pragma unroll
        for (int r = 0; r < 16; ++r){
          const float ar = __shfl(al, (r & 3) + 8 * (r >> 2) + 4 * hi);
          acc[0][r] *= ar; acc[1][r] *= ar; acc[2][r] *= ar; acc[3][r] *= ar;
        }
      }
      float rs = 0.f;
      #pragma unroll
      for (int r = 0; r < 16; ++r){
        const float e0 = __expf(pv0[r] - mx);
        const float e1 = __expf(pv1[r] - mx);
        pv0[r] = e0; pv1[r] = e1;
        rs += e0 + e1;
      }
      rs += __shfl_xor(rs, 32);
      lsum += rs;
      #pragma unroll
      for (int s = 0; s < 4; ++s){
        const int t8 = (s & 1) * 8;
        unsigned w0, w1, w2, w3;
        if (s < 2){
          asm("v_cvt_pk_bf16_f32 %0, %1, %2" : "=v"(w0) : "v"(pv0[t8+0]), "v"(pv0[t8+1]));
          asm("v_cvt_pk_bf16_f32 %0, %1, %2" : "=v"(w1) : "v"(pv0[t8+2]), "v"(pv0[t8+3]));
          asm("v_cvt_pk_bf16_f32 %0, %1, %2" : "=v"(w2) : "v"(pv0[t8+4]), "v"(pv0[t8+5]));
          asm("v_cvt_pk_bf16_f32 %0, %1, %2" : "=v"(w3) : "v"(pv0[t8+6]), "v"(pv0[t8+7]));
        } else {
          asm("v_cvt_pk_bf16_f32 %0, %1, %2" : "=v"(w0) : "v"(pv1[t8+0]), "v"(pv1[t8+1]));
          asm("v_cvt_pk_bf16_f32 %0, %1, %2" : "=v"(w1) : "v"(pv1[t8+2]), "v"(pv1[t8+3]));
          asm("v_cvt_pk_bf16_f32 %0, %1, %2" : "=v"(w2) : "v"(pv1[t8+4]), "v"(pv1[t8+5]));
          asm("v_cvt_pk_bf16_f32 %0, %1, %2" : "=v"(w3) : "v"(pv1[t8+6]), "v"(pv1[t8+7]));
        }
        asm("v_permlane32_swap_b32 %0, %1" : "+v"(w0), "+v"(w2));
        asm("v_permlane32_swap_b32 %0, %1" : "+v"(w1), "+v"(w3));
        u32x4 pw = {w0, w1, w2, w3};
        s16x8 pa = __builtin_bit_cast(s16x8, pw);
        #pragma unroll
        for (int db = 0; db < 4; ++db){
          const int d = db * 32 + l31;
          s16x8 vf = *(const s16x8*)(sVc + d * 128 + (((s * 2 + hi) ^ (d & 7)) << 4));
          MFMA32(acc[db], pa, vf);
        }
      }
    }
    asm volatile("s_waitcnt lgkmcnt(0)");
    __builtin_amdgcn_s_barrier();
  }
  float li[16];
  #pragma unroll
  for (int r = 0; r < 16; ++r)
    li[r] = __shfl(lsum, (r & 3) + 8 * (r >> 2) + 4 * hi);
  #pragma unroll
  for (int db = 0; db < 4; ++db)
    #pragma unroll
    for (int r = 0; r < 16; ++r){
      const int row = qrow0 + (r & 3) + 8 * (r >> 2) + 4 * hi;
      const int col = h * 128 + db * 32 + l31;
      ob[((size_t)(b * 2048) + row) * 2048 + col] = f2b(acc[db][r] / li[r]);
    }
}

extern "C" void kernel_launch(void* const* d_in, const int* in_sizes, int n_in,
                              void* d_out, int out_size, void* d_ws, size_t ws_size,
                              hipStream_t stream){
  const float* hs   = (const float*)d_in[0];
  const float* cosT = (const float*)d_in[1];
  const float* sinT = (const float*)d_in[2];
  const float* Wq = (const float*)d_in[4];
  const float* Wk = (const float*)d_in[5];
  const float* Wv = (const float*)d_in[6];
  const float* Wo = (const float*)d_in[7];
  const float* qw = (const float*)d_in[8];
  const float* kw = (const float*)d_in[9];
  float* out = (float*)d_out;
  char* ws = (char*)d_ws;

  u16*   hsb   = (u16*)(ws);                         // 16 MB (later: q bf16)
  u16*   wqkvT = (u16*)(ws + 16777216);              // 16 MB (later: k,v bf16)
  u16*   woT   = (u16*)(ws + 33554432);              // 8 MB
  u16*   qkvb  = (u16*)(ws + 41943040);              // 32 MB bf16 (freed after rmsrope)
  u16*   qb    = hsb;
  u16*   kb2   = (u16*)(ws + 16777216);
  u16*   vb2   = (u16*)(ws + 16777216 + 8388608);
  u16*   attnb = (u16*)(ws + 41943040);              // 16 MB (aliases dead qkvb lo)
  u16*   vtb   = (u16*)(ws + 41943040 + 16777216);   // 8 MB  (aliases dead qkvb hi)

  k_cast<<<4096, 256, 0, stream>>>(hs, hsb, 1048576);
  k_transpose<<<dim3(64, 64),  256, 0, stream>>>(Wq, wqkvT,                       2048, 2048);
  k_transpose<<<dim3(32, 64),  256, 0, stream>>>(Wk, wqkvT + (size_t)2048 * 2048, 2048, 1024);
  k_transpose<<<dim3(32, 64),  256, 0, stream>>>(Wv, wqkvT + (size_t)3072 * 2048, 2048, 1024);
  k_transpose<<<dim3(64, 64),  256, 0, stream>>>(Wo, woT,                         2048, 2048);
  k_gemm8<4, true><<<dim3(16, 16), 512, 0, stream>>>(hsb, wqkvT, qkvb, 4096, 4096, 2048);
  k_rmsrope<<<4096, 256, 0, stream>>>(qkvb, cosT, sinT, qw, kw, qb, kb2, vb2);
  k_vtrans<<<512, 256, 0, stream>>>(vb2, vtb);
  k_attn<<<512, 256, 0, stream>>>(qb, kb2, vtb, attnb);
  k_gemm8<2, false><<<dim3(16, 16), 512, 0, stream>>>(attnb, woT, out, 4096, 2048, 2048);
}